// Round 7
// baseline (395.107 us; speedup 1.0000x reference)
//
#include <hip/hip_runtime.h>

typedef unsigned short u16;
typedef unsigned int   u32;
typedef __attribute__((ext_vector_type(8))) short short8;
typedef __attribute__((ext_vector_type(4))) float f32x4;

#define LOGM 4.852030263919617f

// workspace layout (float offsets)
constexpr int WS_PMAX = 0;         // 128 floats (per-combo stabilizer bound)
constexpr int WS_K1   = 2048;      // 128*128 floats (k1sum, atomic-accumulated)
constexpr int WS_KV   = 18432;     // 128*128*64 floats (kv [m][d], atomic-accumulated)
constexpr int WS_PHIK = 1067008;   // u16: 128 combos * 1056 * 128 (phi_k bf16, [s][m])
constexpr int WS_PLS  = 9717760;   // 128*1024 floats
constexpr int WS_LR1  = 9848832;   // 128*1024 floats
constexpr int WS_PHIQ = 9979904;   // u16: 128 * 1024 * 128 (phi_q bf16, [q][m])
constexpr int WS_LRV  = 18368512;  // u16: 128 * 1024 * 64 (lr_v bf16, [q][d])

__device__ __forceinline__ float b2f(u16 u){ union { u32 i; float f; } x; x.i = ((u32)u) << 16; return x.f; }
__device__ __forceinline__ u16 f2b(float f){ union { float f; u32 i; } x; x.f = f; return (u16)((x.i + 0x7fffu + ((x.i >> 16) & 1u)) >> 16); }

// ================= k_phi: logk MFMA -> phi_k -> ws; kv & k1 atomics =================
// grid (4,128): kq block owns keys [kq*1024, +1024) as 16 tiles of 64.
// Double-buffered phit/vt => ONE barrier per tile (was 2).
// K row for tile t+1 register-prefetched at top of tile t (hidden under 48 MFMAs).
// True reg footprint ~192 (128 VGPR + 64 AGPR) => 2 waves/SIMD; +16 prefetch regs is free.
__global__ __launch_bounds__(256, 2) void k_phi(const float* __restrict__ key,
                                                const float* __restrict__ val,
                                                const float* __restrict__ proj,
                                                float* __restrict__ ws){
  __shared__ __align__(16) u16 phit[2][128*72];  // [m][key64] bf16, stride 72
  __shared__ __align__(16) u16 vt[2][64*72];     // [d][key64] bf16, stride 72, col-swizzled
  __shared__ float sred[4];
  const int tid = threadIdx.x;
  const int wave = tid >> 6, l = tid & 63;
  const int g = l >> 4, r16 = l & 15;
  const int kq = blockIdx.x, combo = blockIdx.y;
  const int c = combo >> 5, b = (combo >> 3) & 3, h = combo & 7;
  const float* projc = proj + c*8192;

  // prefetch K for tile 0 before the proj setup (latency overlapped with setup)
  float4 ka[4], kb[4];
  {
    const float* krow0 = key + (size_t)(b*4096 + kq*1024 + wave*16 + r16)*512 + h*64;
    ka[0] = *(const float4*)(krow0 + g*8);
    ka[1] = *(const float4*)(krow0 + g*8 + 4);
    ka[2] = *(const float4*)(krow0 + 32 + g*8);
    ka[3] = *(const float4*)(krow0 + 32 + g*8 + 4);
  }

  {
    const float4* pr = (const float4*)(projc + (tid & 127)*64);
    float pn = 0.f;
    #pragma unroll
    for(int i=0;i<16;i++){ float4 u = pr[i]; pn = fmaf(u.x,u.x,fmaf(u.y,u.y,fmaf(u.z,u.z,fmaf(u.w,u.w,pn)))); }
    #pragma unroll
    for(int o=1;o<64;o<<=1) pn = fmaxf(pn, __shfl_xor(pn, o));
    if(l == 0) sred[wave] = pn;
  }
  __syncthreads();
  const float stab = 0.5f * fmaxf(fmaxf(sred[0],sred[1]), fmaxf(sred[2],sred[3]));
  if(kq == 0 && tid == 0) ws[WS_PMAX + combo] = stab;

  short8 ph[8][2], pl[8][2];
  #pragma unroll
  for(int mt=0;mt<8;mt++){
    #pragma unroll
    for(int ks=0;ks<2;ks++){
      const float* pb = projc + (mt*16 + r16)*64 + ks*32 + g*8;
      float4 u0 = *(const float4*)pb;
      float4 u1 = *(const float4*)(pb + 4);
      float x[8] = {u0.x,u0.y,u0.z,u0.w,u1.x,u1.y,u1.z,u1.w};
      #pragma unroll
      for(int j=0;j<8;j++){
        u16 hb = f2b(x[j]);
        ph[mt][ks][j] = (short)hb;
        pl[mt][ks][j] = (short)f2b(x[j] - b2f(hb));
      }
    }
  }

  const f32x4 zero4 = {0.f,0.f,0.f,0.f};
  f32x4 kvacc[2][4];
  #pragma unroll
  for(int i=0;i<2;i++)
    #pragma unroll
    for(int j=0;j<4;j++) kvacc[i][j] = zero4;
  float k1p0 = 0.f, k1p1 = 0.f;
  u16* phikg = ((u16*)(ws + WS_PHIK)) + (size_t)combo*1056*128;

#define PHI_TILE(T0, KC, KN, PB)                                                          \
{                                                                                          \
  const int s_tile = kq*1024 + (T0)*64;                                                    \
  const bool dtile = (s_tile < 1056);                                                      \
  if((T0) < 15){                                                                           \
    const float* krow2 = key + (size_t)(b*4096 + s_tile + 64 + wave*16 + r16)*512 + h*64;  \
    KN[0] = *(const float4*)(krow2 + g*8);                                                 \
    KN[1] = *(const float4*)(krow2 + g*8 + 4);                                             \
    KN[2] = *(const float4*)(krow2 + 32 + g*8);                                            \
    KN[3] = *(const float4*)(krow2 + 32 + g*8 + 4);                                        \
  }                                                                                        \
  float4 vreg[4];                                                                          \
  _Pragma("unroll")                                                                        \
  for(int i=0;i<4;i++){                                                                    \
    int flat = tid + 256*i;                                                                \
    int sv = flat >> 4, d4 = (flat & 15)*4;                                                \
    vreg[i] = *(const float4*)(val + (size_t)(b*4096 + s_tile + sv)*512 + h*64 + d4);      \
  }                                                                                        \
  float areg[16] = {KC[0].x,KC[0].y,KC[0].z,KC[0].w, KC[1].x,KC[1].y,KC[1].z,KC[1].w,      \
                    KC[2].x,KC[2].y,KC[2].z,KC[2].w, KC[3].x,KC[3].y,KC[3].z,KC[3].w};     \
  float ksq = 0.f;                                                                         \
  _Pragma("unroll")                                                                        \
  for(int e=0;e<16;e++) ksq = fmaf(areg[e], areg[e], ksq);                                 \
  ksq += __shfl_xor(ksq, 16); ksq += __shfl_xor(ksq, 32); ksq *= 0.5f;                     \
  short8 ah[2], al[2];                                                                     \
  _Pragma("unroll")                                                                        \
  for(int ks=0;ks<2;ks++){                                                                 \
    _Pragma("unroll")                                                                      \
    for(int j=0;j<8;j++){                                                                  \
      float x = areg[ks*8+j];                                                              \
      u16 hb = f2b(x);                                                                     \
      ah[ks][j] = (short)hb;                                                               \
      al[ks][j] = (short)f2b(x - b2f(hb));                                                 \
    }                                                                                      \
  }                                                                                        \
  f32x4 acc[8];                                                                            \
  _Pragma("unroll")                                                                        \
  for(int mt=0;mt<8;mt++) acc[mt] = zero4;                                                 \
  _Pragma("unroll")                                                                        \
  for(int ks=0;ks<2;ks++){                                                                 \
    _Pragma("unroll")                                                                      \
    for(int mt=0;mt<8;mt++){                                                               \
      acc[mt] = __builtin_amdgcn_mfma_f32_16x16x32_bf16(ah[ks], ph[mt][ks], acc[mt],0,0,0);\
      acc[mt] = __builtin_amdgcn_mfma_f32_16x16x32_bf16(ah[ks], pl[mt][ks], acc[mt],0,0,0);\
      acc[mt] = __builtin_amdgcn_mfma_f32_16x16x32_bf16(al[ks], ph[mt][ks], acc[mt],0,0,0);\
    }                                                                                      \
  }                                                                                        \
  const float kc0 = __shfl(ksq, 4*g + 0);                                                  \
  const float kc1 = __shfl(ksq, 4*g + 1);                                                  \
  const float kc2 = __shfl(ksq, 4*g + 2);                                                  \
  const float kc3 = __shfl(ksq, 4*g + 3);                                                  \
  const int gs = s_tile + wave*16 + r16;                                                   \
  _Pragma("unroll")                                                                        \
  for(int mt=0;mt<8;mt++){                                                                 \
    ushort4 pw;                                                                            \
    pw.x = f2b(__expf(acc[mt][0] - kc0 - stab));                                           \
    pw.y = f2b(__expf(acc[mt][1] - kc1 - stab));                                           \
    pw.z = f2b(__expf(acc[mt][2] - kc2 - stab));                                           \
    pw.w = f2b(__expf(acc[mt][3] - kc3 - stab));                                           \
    *(ushort4*)(phit[PB] + (mt*16 + r16)*72 + wave*16 + 4*g) = pw;                         \
    if(dtile && gs < 1056)                                                                 \
      *(ushort4*)(phikg + (size_t)gs*128 + mt*16 + 4*g) = pw;                              \
  }                                                                                        \
  _Pragma("unroll")                                                                        \
  for(int i=0;i<4;i++){                                                                    \
    int flat = tid + 256*i;                                                                \
    int sv = flat >> 4, d4 = (flat & 15)*4;                                                \
    float xx[4] = {vreg[i].x, vreg[i].y, vreg[i].z, vreg[i].w};                            \
    _Pragma("unroll")                                                                      \
    for(int j=0;j<4;j++){                                                                  \
      int d = d4 + j;                                                                      \
      vt[PB][d*72 + (sv ^ (8*((d>>2)&7)))] = f2b(xx[j]);                                   \
    }                                                                                      \
  }                                                                                        \
  __syncthreads();                                                                         \
  _Pragma("unroll")                                                                        \
  for(int ks=0;ks<2;ks++){                                                                 \
    short8 af0 = *(const short8*)(phit[PB] + ((2*wave+0)*16 + r16)*72 + ks*32 + g*8);      \
    short8 af1 = *(const short8*)(phit[PB] + ((2*wave+1)*16 + r16)*72 + ks*32 + g*8);      \
    short8 bfv[4];                                                                         \
    _Pragma("unroll")                                                                      \
    for(int dt=0;dt<4;dt++){                                                               \
      int d = dt*16 + r16;                                                                 \
      int col = (ks*32 + g*8) ^ (8*((d>>2)&7));                                            \
      bfv[dt] = *(const short8*)(vt[PB] + d*72 + col);                                     \
    }                                                                                      \
    _Pragma("unroll")                                                                      \
    for(int dt=0;dt<4;dt++){                                                               \
      kvacc[0][dt] = __builtin_amdgcn_mfma_f32_16x16x32_bf16(af0, bfv[dt], kvacc[0][dt],0,0,0); \
      kvacc[1][dt] = __builtin_amdgcn_mfma_f32_16x16x32_bf16(af1, bfv[dt], kvacc[1][dt],0,0,0); \
    }                                                                                      \
    _Pragma("unroll")                                                                      \
    for(int j=0;j<8;j++){ k1p0 += b2f((u16)af0[j]); k1p1 += b2f((u16)af1[j]); }            \
  }                                                                                        \
}

  for(int tt=0; tt<16; tt+=2){
    PHI_TILE(tt,   ka, kb, 0)
    PHI_TILE(tt+1, kb, ka, 1)
  }
#undef PHI_TILE

  k1p0 += __shfl_xor(k1p0, 16); k1p0 += __shfl_xor(k1p0, 32);
  k1p1 += __shfl_xor(k1p1, 16); k1p1 += __shfl_xor(k1p1, 32);
  if(l < 16){
    atomicAdd(ws + WS_K1 + combo*128 + (2*wave+0)*16 + l, k1p0);
    atomicAdd(ws + WS_K1 + combo*128 + (2*wave+1)*16 + l, k1p1);
  }
  #pragma unroll
  for(int mi=0;mi<2;mi++){
    #pragma unroll
    for(int dt=0;dt<4;dt++){
      #pragma unroll
      for(int rr=0;rr<4;rr++){
        int m = (2*wave+mi)*16 + 4*g + rr;
        int d = dt*16 + r16;
        atomicAdd(ws + WS_KV + (size_t)combo*8192 + m*64 + d, kvacc[mi][dt][rr]);
      }
    }
  }
}

// ================= k_q: logq MFMA -> phi_q/pls/lr1; lr_v = phi_q . kv MFMA =================
__global__ __launch_bounds__(256, 2) void k_q(const float* __restrict__ qry,
                                              const float* __restrict__ proj,
                                              float* __restrict__ ws){
  __shared__ __align__(16) u16 phiqs[64*136];  // [q][m] bf16, stride 136
  __shared__ __align__(16) u16 kvt[64*136];    // [d][m] bf16
  __shared__ float k1s[128];
  const int tid = threadIdx.x;
  const int wave = tid >> 6, l = tid & 63;
  const int g = l >> 4, r16 = l & 15;
  const int qt = blockIdx.x, combo = blockIdx.y;
  const int c = combo >> 5, b = (combo >> 3) & 3, h = combo & 7;
  const float* projc = proj + c*8192;
  const float stab = ws[WS_PMAX + combo];
  if(tid < 128) k1s[tid] = ws[WS_K1 + combo*128 + tid];
  const float* kvg = ws + WS_KV + (size_t)combo*8192;
  #pragma unroll
  for(int i=0;i<8;i++){
    int flat = tid + 256*i;
    int m = flat >> 4, d4 = (flat & 15)*4;
    float4 u = *(const float4*)(kvg + m*64 + d4);
    kvt[(d4+0)*136 + m] = f2b(u.x);
    kvt[(d4+1)*136 + m] = f2b(u.y);
    kvt[(d4+2)*136 + m] = f2b(u.z);
    kvt[(d4+3)*136 + m] = f2b(u.w);
  }
  const int qrow = qt*64 + wave*16 + r16;
  const float* qr = qry + (size_t)(b*4096 + (c*1024 + qrow))*512 + h*64;
  float areg[16];
  #pragma unroll
  for(int ks=0;ks<2;ks++){
    float4 u0 = *(const float4*)(qr + ks*32 + g*8);
    float4 u1 = *(const float4*)(qr + ks*32 + g*8 + 4);
    areg[ks*8+0]=u0.x; areg[ks*8+1]=u0.y; areg[ks*8+2]=u0.z; areg[ks*8+3]=u0.w;
    areg[ks*8+4]=u1.x; areg[ks*8+5]=u1.y; areg[ks*8+6]=u1.z; areg[ks*8+7]=u1.w;
  }
  float qsq = 0.f;
  #pragma unroll
  for(int e=0;e<16;e++) qsq = fmaf(areg[e], areg[e], qsq);
  qsq += __shfl_xor(qsq, 16);
  qsq += __shfl_xor(qsq, 32);
  qsq *= 0.5f;
  short8 ah[2], al[2];
  #pragma unroll
  for(int ks=0;ks<2;ks++){
    #pragma unroll
    for(int j=0;j<8;j++){
      float x = areg[ks*8+j];
      u16 hb = f2b(x);
      ah[ks][j] = (short)hb;
      al[ks][j] = (short)f2b(x - b2f(hb));
    }
  }
  const f32x4 zero4 = {0.f,0.f,0.f,0.f};
  f32x4 acc[8];
  #pragma unroll
  for(int mt=0;mt<8;mt++) acc[mt] = zero4;
  #pragma unroll
  for(int ks=0;ks<2;ks++){
    #pragma unroll
    for(int mt=0;mt<8;mt++){
      const float* pb = projc + (mt*16 + r16)*64 + ks*32 + g*8;
      float4 u0 = *(const float4*)pb;
      float4 u1 = *(const float4*)(pb + 4);
      float x[8] = {u0.x,u0.y,u0.z,u0.w,u1.x,u1.y,u1.z,u1.w};
      short8 pph, ppl;
      #pragma unroll
      for(int j=0;j<8;j++){
        u16 hb = f2b(x[j]);
        pph[j] = (short)hb;
        ppl[j] = (short)f2b(x[j] - b2f(hb));
      }
      acc[mt] = __builtin_amdgcn_mfma_f32_16x16x32_bf16(ah[ks], pph, acc[mt], 0, 0, 0);
      acc[mt] = __builtin_amdgcn_mfma_f32_16x16x32_bf16(ah[ks], ppl, acc[mt], 0, 0, 0);
      acc[mt] = __builtin_amdgcn_mfma_f32_16x16x32_bf16(al[ks], pph, acc[mt], 0, 0, 0);
    }
  }
  float qsr[4];
  #pragma unroll
  for(int r=0;r<4;r++) qsr[r] = __shfl(qsq, 4*g + r);
  float amax[4];
  #pragma unroll
  for(int r=0;r<4;r++){
    float m = -3e38f;
    #pragma unroll
    for(int mt=0;mt<8;mt++) m = fmaxf(m, acc[mt][r]);
    m = fmaxf(m, __shfl_xor(m, 1));
    m = fmaxf(m, __shfl_xor(m, 2));
    m = fmaxf(m, __shfl_xor(m, 4));
    m = fmaxf(m, __shfl_xor(m, 8));
    amax[r] = m;
  }
  float lrp[4] = {0.f,0.f,0.f,0.f};
  #pragma unroll
  for(int mt=0;mt<8;mt++){
    const float k1v = k1s[mt*16 + r16];
    #pragma unroll
    for(int r=0;r<4;r++){
      float phv = __expf(acc[mt][r] - amax[r]);
      phiqs[(wave*16 + 4*g + r)*136 + mt*16 + r16] = f2b(phv);
      lrp[r] = fmaf(phv, k1v, lrp[r]);
    }
  }
  #pragma unroll
  for(int r=0;r<4;r++){
    lrp[r] += __shfl_xor(lrp[r], 1);
    lrp[r] += __shfl_xor(lrp[r], 2);
    lrp[r] += __shfl_xor(lrp[r], 4);
    lrp[r] += __shfl_xor(lrp[r], 8);
  }
  if(r16 == 0){
    #pragma unroll
    for(int r=0;r<4;r++){
      int row = qt*64 + wave*16 + 4*g + r;
      ws[WS_PLS + combo*1024 + row] = amax[r] - qsr[r] + stab - LOGM;
      ws[WS_LR1 + combo*1024 + row] = lrp[r];
    }
  }
  __syncthreads();
  f32x4 lacc[4];
  #pragma unroll
  for(int dt=0;dt<4;dt++) lacc[dt] = zero4;
  #pragma unroll
  for(int ks=0;ks<4;ks++){
    short8 a = *(const short8*)(phiqs + (wave*16 + r16)*136 + ks*32 + g*8);
    #pragma unroll
    for(int dt=0;dt<4;dt++){
      short8 bfr = *(const short8*)(kvt + (dt*16 + r16)*136 + ks*32 + g*8);
      lacc[dt] = __builtin_amdgcn_mfma_f32_16x16x32_bf16(a, bfr, lacc[dt], 0, 0, 0);
    }
  }
  u16* lrvg = ((u16*)(ws + WS_LRV)) + ((size_t)combo*1024 + qt*64)*64;
  #pragma unroll
  for(int dt=0;dt<4;dt++){
    #pragma unroll
    for(int r=0;r<4;r++)
      lrvg[(wave*16 + 4*g + r)*64 + dt*16 + r16] = f2b(lacc[dt][r]);
  }
  u16* phiqg = ((u16*)(ws + WS_PHIQ)) + ((size_t)combo*1024 + qt*64)*128;
  #pragma unroll
  for(int i=0;i<8;i++){
    int flat = tid + 256*i;
    int row = flat >> 5, c4 = (flat & 31)*4;
    *(ushort4*)(phiqg + flat*4) = *(const ushort4*)(phiqs + row*136 + c4);
  }
}

// ================= k_main (MFMA): local window + combine =================
__global__ __launch_bounds__(256, 2) void k_main(const float* __restrict__ qry,
                                                 const float* __restrict__ key,
                                                 const float* __restrict__ val,
                                                 float* __restrict__ ws,
                                                 float* __restrict__ out){
  // one phase-overlaid buffer (u16 offsets, all rows 16B-aligned):
  //  phase1: kh @0 [96][72], kl @6912 [96][72], phik @13824 [96][136]   (end 26880)
  //  phase2/3: cjh @0 [64][136], cjl @8704, vt @17408 [64][104], vtl @24064
  __shared__ __align__(16) u16 buf[30720];   // 61440 B
  u16* khs  = buf;
  u16* kls  = buf + 6912;
  u16* phik = buf + 13824;
  u16* cjh  = buf;
  u16* cjl  = buf + 8704;
  u16* vt   = buf + 17408;
  u16* vtl  = buf + 24064;

  const int tid = threadIdx.x;
  const int wave = tid >> 6, l = tid & 63;
  const int g = l >> 4, r16 = l & 15;
  const int qt = blockIdx.x, combo = blockIdx.y;
  const int c = combo >> 5, b = (combo >> 3) & 3, h = combo & 7;
  const int s_base = qt*64 - 16;

  // ---- phase 0: stage k (hi/lo) + phi_k window into LDS; v into regs (T14 split)
  const u16* phikg = ((const u16*)(ws + WS_PHIK)) + (size_t)combo*1056*128;
  float4 vreg[6];
  #pragma unroll
  for(int i=0;i<6;i++){
    int flat = tid + 256*i;
    int j = flat >> 4, e4 = (flat & 15)*4;
    int s = s_base + j;
    float4 u = {0.f,0.f,0.f,0.f};
    float4 w4 = {0.f,0.f,0.f,0.f};
    if(s >= 0){
      u  = *(const float4*)(key + (((size_t)b*4096 + s)*8 + h)*64 + e4);
      w4 = *(const float4*)(val + (((size_t)b*4096 + s)*8 + h)*64 + e4);
    }
    vreg[i] = w4;
    ushort4 hh, ll;
    hh.x = f2b(u.x); ll.x = f2b(u.x - b2f(hh.x));
    hh.y = f2b(u.y); ll.y = f2b(u.y - b2f(hh.y));
    hh.z = f2b(u.z); ll.z = f2b(u.z - b2f(hh.z));
    hh.w = f2b(u.w); ll.w = f2b(u.w - b2f(hh.w));
    *(ushort4*)(khs + j*72 + e4) = hh;
    *(ushort4*)(kls + j*72 + e4) = ll;
  }
  #pragma unroll
  for(int i=0;i<12;i++){
    int flat = tid + 256*i;
    int j = flat >> 5, c4 = (flat & 31)*4;
    int s = s_base + j;
    ushort4 p = {0,0,0,0};
    if(s >= 0) p = *(const ushort4*)(phikg + (size_t)s*128 + c4);
    *(ushort4*)(phik + j*136 + c4) = p;
  }
  // wave-private A-fragments: q rows (hi/lo split) + phi_q rows
  const int qrow = qt*64 + wave*16 + r16;    // this lane's A-row (query)
  const float* qr = qry + (((size_t)b*4096 + (c*1024 + qrow))*8 + h)*64;
  short8 ah[2], al[2];
  #pragma unroll
  for(int ks=0;ks<2;ks++){
    float4 u0 = *(const float4*)(qr + ks*32 + g*8);
    float4 u1 = *(const float4*)(qr + ks*32 + g*8 + 4);
    float x[8] = {u0.x,u0.y,u0.z,u0.w,u1.x,u1.y,u1.z,u1.w};
    #pragma unroll
    for(int jj=0;jj<8;jj++){
      u16 hb = f2b(x[jj]);
      ah[ks][jj] = (short)hb;
      al[ks][jj] = (short)f2b(x[jj] - b2f(hb));
    }
  }
  const u16* phiqg = ((const u16*)(ws + WS_PHIQ)) + ((size_t)combo*1024 + qt*64)*128;
  short8 pa[4];
  #pragma unroll
  for(int ks=0;ks<4;ks++)
    pa[ks] = *(const short8*)(phiqg + (wave*16 + r16)*128 + ks*32 + g*8);
  // per-query scalars for this lane's 4 C-rows (row = wave*16 + 4g + r)
  float plsr[4], lr1r[4];
  #pragma unroll
  for(int r=0;r<4;r++){
    int row = qt*64 + wave*16 + 4*g + r;
    plsr[r] = ws[WS_PLS + combo*1024 + row];
    lr1r[r] = ws[WS_LR1 + combo*1024 + row];
  }
  __syncthreads();

  // ---- phase 1: S (scores) and D (dots_p) over the full 16x96 stripe
  const f32x4 zero4 = {0.f,0.f,0.f,0.f};
  f32x4 sacc[6], dacc[6];
  #pragma unroll
  for(int j=0;j<6;j++){ sacc[j] = zero4; dacc[j] = zero4; }
  #pragma unroll
  for(int j=0;j<6;j++){
    #pragma unroll
    for(int ks=0;ks<2;ks++){
      short8 kbh = *(const short8*)(khs + (j*16 + r16)*72 + ks*32 + g*8);
      short8 kbl = *(const short8*)(kls + (j*16 + r16)*72 + ks*32 + g*8);
      sacc[j] = __builtin_amdgcn_mfma_f32_16x16x32_bf16(ah[ks], kbh, sacc[j], 0, 0, 0);
      sacc[j] = __builtin_amdgcn_mfma_f32_16x16x32_bf16(al[ks], kbh, sacc[j], 0, 0, 0);
      sacc[j] = __builtin_amdgcn_mfma_f32_16x16x32_bf16(ah[ks], kbl, sacc[j], 0, 0, 0);
    }
    #pragma unroll
    for(int ks=0;ks<4;ks++){
      short8 pb = *(const short8*)(phik + (j*16 + r16)*136 + ks*32 + g*8);
      dacc[j] = __builtin_amdgcn_mfma_f32_16x16x32_bf16(pa[ks], pb, dacc[j], 0, 0, 0);
    }
  }
  __syncthreads();   // all phase-1 LDS reads done; region reused below

  // ---- phase 2: v -> LDS (transposed, hi/lo); in-register softmax/normalizer; cj -> LDS
  #pragma unroll
  for(int i=0;i<6;i++){
    int flat = tid + 256*i;
    int j = flat >> 4, e4 = (flat & 15)*4;
    float4 u = vreg[i];
    u16 h0 = f2b(u.x), h1 = f2b(u.y), h2 = f2b(u.z), h3 = f2b(u.w);
    vt[(e4+0)*104 + j] = h0; vtl[(e4+0)*104 + j] = f2b(u.x - b2f(h0));
    vt[(e4+1)*104 + j] = h1; vtl[(e4+1)*104 + j] = f2b(u.y - b2f(h1));
    vt[(e4+2)*104 + j] = h2; vtl[(e4+2)*104 + j] = f2b(u.z - b2f(h2));
    vt[(e4+3)*104 + j] = h3; vtl[(e4+3)*104 + j] = f2b(u.w - b2f(h3));
  }
  // band mask: C-layout row = 4g+r (query), col = r16 (key within tile j)
  const int rowb = wave*16 + 4*g;
  float m1r[4] = {-1e30f,-1e30f,-1e30f,-1e30f};
  #pragma unroll
  for(int j=0;j<6;j++){
    #pragma unroll
    for(int r=0;r<4;r++){
      int rel = 16*j + r16 - 16 - (rowb + r);
      bool ok = (rel >= -16) && (rel < 16) && (s_base + 16*j + r16 >= 0);
      if(ok) m1r[r] = fmaxf(m1r[r], sacc[j][r]);
    }
  }
  #pragma unroll
  for(int r=0;r<4;r++){
    m1r[r] = fmaxf(m1r[r], __shfl_xor(m1r[r], 1));
    m1r[r] = fmaxf(m1r[r], __shfl_xor(m1r[r], 2));
    m1r[r] = fmaxf(m1r[r], __shfl_xor(m1r[r], 4));
    m1r[r] = fmaxf(m1r[r], __shfl_xor(m1r[r], 8));
  }
  float ser[4] = {0.f,0.f,0.f,0.f}, wpr[4] = {0.f,0.f,0.f,0.f};
  #pragma unroll
  for(int j=0;j<6;j++){
    #pragma unroll
    for(int r=0;r<4;r++){
      int rel = 16*j + r16 - 16 - (rowb + r);
      bool ok = (rel >= -16) && (rel < 16) && (s_base + 16*j + r16 >= 0);
      if(ok){
        ser[r] += __expf(sacc[j][r] - m1r[r]);
        wpr[r] += dacc[j][r];
      }
    }
  }
  #pragma unroll
  for(int r=0;r<4;r++){
    ser[r] += __shfl_xor(ser[r], 1); ser[r] += __shfl_xor(ser[r], 2);
    ser[r] += __shfl_xor(ser[r], 4); ser[r] += __shfl_xor(ser[r], 8);
    wpr[r] += __shfl_xor(wpr[r], 1); wpr[r] += __shfl_xor(wpr[r], 2);
    wpr[r] += __shfl_xor(wpr[r], 4); wpr[r] += __shfl_xor(wpr[r], 8);
  }
  float lnr[4], scr[4];
  #pragma unroll
  for(int r=0;r<4;r++){
    float qk_lse = m1r[r] + __logf(ser[r]);
    float lrem = fmaxf(lr1r[r] - wpr[r], 1e-37f);
    float bb = __logf(lrem) + plsr[r];
    float ln = fmaxf(qk_lse, bb) + log1pf(__expf(-fabsf(qk_lse - bb)));
    lnr[r] = ln;
    scr[r] = __expf(plsr[r] - ln);
  }
  #pragma unroll
  for(int j=0;j<6;j++){
    #pragma unroll
    for(int r=0;r<4;r++){
      int rel = 16*j + r16 - 16 - (rowb + r);
      bool ok = (rel >= -16) && (rel < 16) && (s_base + 16*j + r16 >= 0);
      float cj = ok ? (__expf(sacc[j][r] - lnr[r]) - scr[r]*dacc[j][r]) : 0.f;
      u16 hb = f2b(cj);
      cjh[(rowb + r)*136 + 16*j + r16] = hb;
      cjl[(rowb + r)*136 + 16*j + r16] = f2b(cj - b2f(hb));
    }
  }
  __syncthreads();

  // ---- phase 3: out = cj . v_win (hi/lo split) + scale*lr_v
  f32x4 oacc[4];
  #pragma unroll
  for(int dt=0;dt<4;dt++) oacc[dt] = zero4;
  #pragma unroll
  for(int ks=0;ks<3;ks++){
    short8 ch = *(const short8*)(cjh + (wave*16 + r16)*136 + ks*32 + g*8);
    short8 cl = *(const short8*)(cjl + (wave*16 + r16)*136 + ks*32 + g*8);
    #pragma unroll
    for(int dt=0;dt<4;dt++){
      short8 vbh = *(const short8*)(vt  + (dt*16 + r16)*104 + ks*32 + g*8);
      short8 vbl = *(const short8*)(vtl + (dt*16 + r16)*104 + ks*32 + g*8);
      oacc[dt] = __builtin_amdgcn_mfma_f32_16x16x32_bf16(ch, vbh, oacc[dt], 0, 0, 0);
      oacc[dt] = __builtin_amdgcn_mfma_f32_16x16x32_bf16(cl, vbh, oacc[dt], 0, 0, 0);
      oacc[dt] = __builtin_amdgcn_mfma_f32_16x16x32_bf16(ch, vbl, oacc[dt], 0, 0, 0);
    }
  }
  const u16* lrvg = ((const u16*)(ws + WS_LRV)) + ((size_t)combo*1024 + qt*64)*64;
  #pragma unroll
  for(int r=0;r<4;r++){
    int row = rowb + r;                      // query within 64
    float* ob = out + ((((size_t)b*8 + h)*4096) + (size_t)c*1024 + qt*64 + row)*64;
    #pragma unroll
    for(int dt=0;dt<4;dt++){
      float lv = b2f(lrvg[row*64 + dt*16 + r16]);
      ob[dt*16 + r16] = oacc[dt][r] + scr[r]*lv;
    }
  }
}

extern "C" void kernel_launch(void* const* d_in, const int* in_sizes, int n_in,
                              void* d_out, int out_size, void* d_ws, size_t ws_size,
                              hipStream_t stream){
  (void)in_sizes; (void)n_in; (void)out_size; (void)ws_size;
  const float* q = (const float*)d_in[0];
  const float* k = (const float*)d_in[1];
  const float* v = (const float*)d_in[2];
  const float* p = (const float*)d_in[3];
  float* out = (float*)d_out;
  float* ws = (float*)d_ws;
  hipMemsetAsync(ws + WS_K1, 0, (size_t)(16384 + 1048576)*sizeof(float), stream);
  k_phi <<<dim3(4,128),  256, 0, stream>>>(k, v, p, ws);
  k_q   <<<dim3(16,128), 256, 0, stream>>>(q, p, ws);
  k_main<<<dim3(16,128), 256, 0, stream>>>(q, k, v, ws, out);
}

// Round 8
// 385.063 us; speedup vs baseline: 1.0261x; 1.0261x over previous
//
#include <hip/hip_runtime.h>

typedef unsigned short u16;
typedef unsigned int   u32;
typedef __attribute__((ext_vector_type(8))) short short8;
typedef __attribute__((ext_vector_type(4))) float f32x4;

#define LOGM 4.852030263919617f

// workspace layout (float offsets)
constexpr int WS_PMAX = 0;         // 128 floats (per-combo stabilizer bound)
constexpr int WS_K1   = 2048;      // 128*128 floats (k1sum, atomic-accumulated)
constexpr int WS_KV   = 18432;     // 128*128*64 floats (kv [m][d], atomic-accumulated)
constexpr int WS_PHIK = 1067008;   // u16: 128 combos * 1056 * 128 (phi_k bf16, [s][m])
constexpr int WS_PLS  = 9717760;   // 128*1024 floats
constexpr int WS_LR1  = 9848832;   // 128*1024 floats
constexpr int WS_PHIQ = 9979904;   // u16: 128 * 1024 * 128 (phi_q bf16, [q][m])
constexpr int WS_LRV  = 18368512;  // u16: 128 * 1024 * 64 (lr_v bf16, [q][d])

__device__ __forceinline__ float b2f(u16 u){ union { u32 i; float f; } x; x.i = ((u32)u) << 16; return x.f; }
__device__ __forceinline__ u16 f2b(float f){ union { float f; u32 i; } x; x.f = f; return (u16)((x.i + 0x7fffu + ((x.i >> 16) & 1u)) >> 16); }

// ================= k_phi: logk MFMA -> phi_k -> ws; kv & k1 atomics =================
// grid (8,128): blockIdx.x = kq*2 + mh. kq block owns keys [kq*1024,+1024) as 16 tiles
// of 64; mh block owns feature half m in [mh*64, mh*64+64).
// m-split halves ph/pl (32 VGPR), acc (16), kvacc (16) => ~140 regs/wave =>
// __launch_bounds__(256,3) gives 3 waves/SIMD (1.5x latency hiding) WITHOUT spills
// (r5 lesson: only request occupancy the natural register usage supports).
__global__ __launch_bounds__(256, 3) void k_phi(const float* __restrict__ key,
                                                const float* __restrict__ val,
                                                const float* __restrict__ proj,
                                                float* __restrict__ ws){
  __shared__ __align__(16) u16 phit[64*72];    // [m_local][key64] bf16, stride 72
  __shared__ __align__(16) u16 vt[64*72];      // [d][key64] bf16, stride 72, col-swizzled
  __shared__ float sred[4];
  const int tid = threadIdx.x;
  const int wave = tid >> 6, l = tid & 63;
  const int g = l >> 4, r16 = l & 15;
  const int kq = blockIdx.x >> 1, mh = blockIdx.x & 1;
  const int combo = blockIdx.y;
  const int c = combo >> 5, b = (combo >> 3) & 3, h = combo & 7;
  const float* projc = proj + c*8192;

  {
    // stab is a max over ALL 128 proj rows (both mh halves compute the same value)
    const float4* pr = (const float4*)(projc + (tid & 127)*64);
    float pn = 0.f;
    #pragma unroll
    for(int i=0;i<16;i++){ float4 u = pr[i]; pn = fmaf(u.x,u.x,fmaf(u.y,u.y,fmaf(u.z,u.z,fmaf(u.w,u.w,pn)))); }
    #pragma unroll
    for(int o=1;o<64;o<<=1) pn = fmaxf(pn, __shfl_xor(pn, o));
    if(l == 0) sred[wave] = pn;
  }
  __syncthreads();
  const float stab = 0.5f * fmaxf(fmaxf(sred[0],sred[1]), fmaxf(sred[2],sred[3]));
  if(kq == 0 && mh == 0 && tid == 0) ws[WS_PMAX + combo] = stab;

  short8 ph[4][2], pl[4][2];
  #pragma unroll
  for(int mt=0;mt<4;mt++){
    #pragma unroll
    for(int ks=0;ks<2;ks++){
      const float* pb = projc + (mh*64 + mt*16 + r16)*64 + ks*32 + g*8;
      float4 u0 = *(const float4*)pb;
      float4 u1 = *(const float4*)(pb + 4);
      float x[8] = {u0.x,u0.y,u0.z,u0.w,u1.x,u1.y,u1.z,u1.w};
      #pragma unroll
      for(int j=0;j<8;j++){
        u16 hb = f2b(x[j]);
        ph[mt][ks][j] = (short)hb;
        pl[mt][ks][j] = (short)f2b(x[j] - b2f(hb));
      }
    }
  }

  const f32x4 zero4 = {0.f,0.f,0.f,0.f};
  f32x4 kvacc[4];   // this wave owns m_local group = wave (16 m), all 64 d
  #pragma unroll
  for(int j=0;j<4;j++) kvacc[j] = zero4;
  float k1p = 0.f;
  u16* phikg = ((u16*)(ws + WS_PHIK)) + (size_t)combo*1056*128;

  for(int t0=0;t0<16;t0++){
    const int s_tile = kq*1024 + t0*64;
    const bool dtile = (s_tile < 1056);
    const int sA = s_tile + wave*16 + r16;
    const float* krow = key + (size_t)(b*4096 + sA)*512 + h*64;
    float areg[16];
    #pragma unroll
    for(int ks=0;ks<2;ks++){
      float4 u0 = *(const float4*)(krow + ks*32 + g*8);
      float4 u1 = *(const float4*)(krow + ks*32 + g*8 + 4);
      areg[ks*8+0]=u0.x; areg[ks*8+1]=u0.y; areg[ks*8+2]=u0.z; areg[ks*8+3]=u0.w;
      areg[ks*8+4]=u1.x; areg[ks*8+5]=u1.y; areg[ks*8+6]=u1.z; areg[ks*8+7]=u1.w;
    }
    // issue v loads now; consumed after the MFMA block (latency hidden under compute)
    float4 vreg[4];
    #pragma unroll
    for(int i=0;i<4;i++){
      int flat = tid + 256*i;
      int sv = flat >> 4, d4 = (flat & 15)*4;
      vreg[i] = *(const float4*)(val + (size_t)(b*4096 + s_tile + sv)*512 + h*64 + d4);
    }
    float ksq = 0.f;
    #pragma unroll
    for(int e=0;e<16;e++) ksq = fmaf(areg[e], areg[e], ksq);
    ksq += __shfl_xor(ksq, 16);
    ksq += __shfl_xor(ksq, 32);
    ksq *= 0.5f;
    short8 ah[2], al[2];
    #pragma unroll
    for(int ks=0;ks<2;ks++){
      #pragma unroll
      for(int j=0;j<8;j++){
        float x = areg[ks*8+j];
        u16 hb = f2b(x);
        ah[ks][j] = (short)hb;
        al[ks][j] = (short)f2b(x - b2f(hb));
      }
    }
    f32x4 acc[4];
    #pragma unroll
    for(int mt=0;mt<4;mt++) acc[mt] = zero4;
    #pragma unroll
    for(int ks=0;ks<2;ks++){
      #pragma unroll
      for(int mt=0;mt<4;mt++){
        acc[mt] = __builtin_amdgcn_mfma_f32_16x16x32_bf16(ah[ks], ph[mt][ks], acc[mt], 0, 0, 0);
        acc[mt] = __builtin_amdgcn_mfma_f32_16x16x32_bf16(ah[ks], pl[mt][ks], acc[mt], 0, 0, 0);
        acc[mt] = __builtin_amdgcn_mfma_f32_16x16x32_bf16(al[ks], ph[mt][ks], acc[mt], 0, 0, 0);
      }
    }
    const float kc0 = __shfl(ksq, 4*g + 0);
    const float kc1 = __shfl(ksq, 4*g + 1);
    const float kc2 = __shfl(ksq, 4*g + 2);
    const float kc3 = __shfl(ksq, 4*g + 3);
    const int gs = s_tile + wave*16 + r16;
    #pragma unroll
    for(int mt=0;mt<4;mt++){
      ushort4 pw;
      pw.x = f2b(__expf(acc[mt][0] - kc0 - stab));
      pw.y = f2b(__expf(acc[mt][1] - kc1 - stab));
      pw.z = f2b(__expf(acc[mt][2] - kc2 - stab));
      pw.w = f2b(__expf(acc[mt][3] - kc3 - stab));
      *(ushort4*)(phit + (mt*16 + r16)*72 + wave*16 + 4*g) = pw;
      // direct register->global scatter (same expression as r3/r6, + mh column base)
      if(dtile && gs < 1056)
        *(ushort4*)(phikg + (size_t)gs*128 + mh*64 + mt*16 + 4*g) = pw;
    }
    // vt store, col-swizzled: (d, s) -> d*72 + (s ^ 8*((d>>2)&7))
    #pragma unroll
    for(int i=0;i<4;i++){
      int flat = tid + 256*i;
      int sv = flat >> 4, d4 = (flat & 15)*4;
      float x[4] = {vreg[i].x, vreg[i].y, vreg[i].z, vreg[i].w};
      #pragma unroll
      for(int j=0;j<4;j++){
        int d = d4 + j;
        vt[d*72 + (sv ^ (8*((d>>2)&7)))] = f2b(x[j]);
      }
    }
    __syncthreads();
    #pragma unroll
    for(int ks=0;ks<2;ks++){
      short8 af = *(const short8*)(phit + (wave*16 + r16)*72 + ks*32 + g*8);
      short8 bf[4];
      #pragma unroll
      for(int dt=0;dt<4;dt++){
        int d = dt*16 + r16;
        int col = (ks*32 + g*8) ^ (8*((d>>2)&7));
        bf[dt] = *(const short8*)(vt + d*72 + col);
      }
      #pragma unroll
      for(int dt=0;dt<4;dt++)
        kvacc[dt] = __builtin_amdgcn_mfma_f32_16x16x32_bf16(af, bf[dt], kvacc[dt], 0, 0, 0);
      #pragma unroll
      for(int j=0;j<8;j++) k1p += b2f((u16)af[j]);
    }
    __syncthreads();
  }
  k1p += __shfl_xor(k1p, 16); k1p += __shfl_xor(k1p, 32);
  if(l < 16)
    atomicAdd(ws + WS_K1 + combo*128 + mh*64 + wave*16 + l, k1p);
  #pragma unroll
  for(int dt=0;dt<4;dt++){
    #pragma unroll
    for(int rr=0;rr<4;rr++){
      int m = mh*64 + wave*16 + 4*g + rr;
      int d = dt*16 + r16;
      atomicAdd(ws + WS_KV + (size_t)combo*8192 + m*64 + d, kvacc[dt][rr]);
    }
  }
}

// ================= k_q: logq MFMA -> phi_q/pls/lr1; lr_v = phi_q . kv MFMA =================
__global__ __launch_bounds__(256, 2) void k_q(const float* __restrict__ qry,
                                              const float* __restrict__ proj,
                                              float* __restrict__ ws){
  __shared__ __align__(16) u16 phiqs[64*136];  // [q][m] bf16, stride 136
  __shared__ __align__(16) u16 kvt[64*136];    // [d][m] bf16
  __shared__ float k1s[128];
  const int tid = threadIdx.x;
  const int wave = tid >> 6, l = tid & 63;
  const int g = l >> 4, r16 = l & 15;
  const int qt = blockIdx.x, combo = blockIdx.y;
  const int c = combo >> 5, b = (combo >> 3) & 3, h = combo & 7;
  const float* projc = proj + c*8192;
  const float stab = ws[WS_PMAX + combo];
  if(tid < 128) k1s[tid] = ws[WS_K1 + combo*128 + tid];
  const float* kvg = ws + WS_KV + (size_t)combo*8192;
  #pragma unroll
  for(int i=0;i<8;i++){
    int flat = tid + 256*i;
    int m = flat >> 4, d4 = (flat & 15)*4;
    float4 u = *(const float4*)(kvg + m*64 + d4);
    kvt[(d4+0)*136 + m] = f2b(u.x);
    kvt[(d4+1)*136 + m] = f2b(u.y);
    kvt[(d4+2)*136 + m] = f2b(u.z);
    kvt[(d4+3)*136 + m] = f2b(u.w);
  }
  const int qrow = qt*64 + wave*16 + r16;
  const float* qr = qry + (size_t)(b*4096 + (c*1024 + qrow))*512 + h*64;
  float areg[16];
  #pragma unroll
  for(int ks=0;ks<2;ks++){
    float4 u0 = *(const float4*)(qr + ks*32 + g*8);
    float4 u1 = *(const float4*)(qr + ks*32 + g*8 + 4);
    areg[ks*8+0]=u0.x; areg[ks*8+1]=u0.y; areg[ks*8+2]=u0.z; areg[ks*8+3]=u0.w;
    areg[ks*8+4]=u1.x; areg[ks*8+5]=u1.y; areg[ks*8+6]=u1.z; areg[ks*8+7]=u1.w;
  }
  float qsq = 0.f;
  #pragma unroll
  for(int e=0;e<16;e++) qsq = fmaf(areg[e], areg[e], qsq);
  qsq += __shfl_xor(qsq, 16);
  qsq += __shfl_xor(qsq, 32);
  qsq *= 0.5f;
  short8 ah[2], al[2];
  #pragma unroll
  for(int ks=0;ks<2;ks++){
    #pragma unroll
    for(int j=0;j<8;j++){
      float x = areg[ks*8+j];
      u16 hb = f2b(x);
      ah[ks][j] = (short)hb;
      al[ks][j] = (short)f2b(x - b2f(hb));
    }
  }
  const f32x4 zero4 = {0.f,0.f,0.f,0.f};
  f32x4 acc[8];
  #pragma unroll
  for(int mt=0;mt<8;mt++) acc[mt] = zero4;
  #pragma unroll
  for(int ks=0;ks<2;ks++){
    #pragma unroll
    for(int mt=0;mt<8;mt++){
      const float* pb = projc + (mt*16 + r16)*64 + ks*32 + g*8;
      float4 u0 = *(const float4*)pb;
      float4 u1 = *(const float4*)(pb + 4);
      float x[8] = {u0.x,u0.y,u0.z,u0.w,u1.x,u1.y,u1.z,u1.w};
      short8 pph, ppl;
      #pragma unroll
      for(int j=0;j<8;j++){
        u16 hb = f2b(x[j]);
        pph[j] = (short)hb;
        ppl[j] = (short)f2b(x[j] - b2f(hb));
      }
      acc[mt] = __builtin_amdgcn_mfma_f32_16x16x32_bf16(ah[ks], pph, acc[mt], 0, 0, 0);
      acc[mt] = __builtin_amdgcn_mfma_f32_16x16x32_bf16(ah[ks], ppl, acc[mt], 0, 0, 0);
      acc[mt] = __builtin_amdgcn_mfma_f32_16x16x32_bf16(al[ks], pph, acc[mt], 0, 0, 0);
    }
  }
  float qsr[4];
  #pragma unroll
  for(int r=0;r<4;r++) qsr[r] = __shfl(qsq, 4*g + r);
  float amax[4];
  #pragma unroll
  for(int r=0;r<4;r++){
    float m = -3e38f;
    #pragma unroll
    for(int mt=0;mt<8;mt++) m = fmaxf(m, acc[mt][r]);
    m = fmaxf(m, __shfl_xor(m, 1));
    m = fmaxf(m, __shfl_xor(m, 2));
    m = fmaxf(m, __shfl_xor(m, 4));
    m = fmaxf(m, __shfl_xor(m, 8));
    amax[r] = m;
  }
  float lrp[4] = {0.f,0.f,0.f,0.f};
  #pragma unroll
  for(int mt=0;mt<8;mt++){
    const float k1v = k1s[mt*16 + r16];
    #pragma unroll
    for(int r=0;r<4;r++){
      float phv = __expf(acc[mt][r] - amax[r]);
      phiqs[(wave*16 + 4*g + r)*136 + mt*16 + r16] = f2b(phv);
      lrp[r] = fmaf(phv, k1v, lrp[r]);
    }
  }
  #pragma unroll
  for(int r=0;r<4;r++){
    lrp[r] += __shfl_xor(lrp[r], 1);
    lrp[r] += __shfl_xor(lrp[r], 2);
    lrp[r] += __shfl_xor(lrp[r], 4);
    lrp[r] += __shfl_xor(lrp[r], 8);
  }
  if(r16 == 0){
    #pragma unroll
    for(int r=0;r<4;r++){
      int row = qt*64 + wave*16 + 4*g + r;
      ws[WS_PLS + combo*1024 + row] = amax[r] - qsr[r] + stab - LOGM;
      ws[WS_LR1 + combo*1024 + row] = lrp[r];
    }
  }
  __syncthreads();
  f32x4 lacc[4];
  #pragma unroll
  for(int dt=0;dt<4;dt++) lacc[dt] = zero4;
  #pragma unroll
  for(int ks=0;ks<4;ks++){
    short8 a = *(const short8*)(phiqs + (wave*16 + r16)*136 + ks*32 + g*8);
    #pragma unroll
    for(int dt=0;dt<4;dt++){
      short8 bfr = *(const short8*)(kvt + (dt*16 + r16)*136 + ks*32 + g*8);
      lacc[dt] = __builtin_amdgcn_mfma_f32_16x16x32_bf16(a, bfr, lacc[dt], 0, 0, 0);
    }
  }
  u16* lrvg = ((u16*)(ws + WS_LRV)) + ((size_t)combo*1024 + qt*64)*64;
  #pragma unroll
  for(int dt=0;dt<4;dt++){
    #pragma unroll
    for(int r=0;r<4;r++)
      lrvg[(wave*16 + 4*g + r)*64 + dt*16 + r16] = f2b(lacc[dt][r]);
  }
  u16* phiqg = ((u16*)(ws + WS_PHIQ)) + ((size_t)combo*1024 + qt*64)*128;
  #pragma unroll
  for(int i=0;i<8;i++){
    int flat = tid + 256*i;
    int row = flat >> 5, c4 = (flat & 31)*4;
    *(ushort4*)(phiqg + flat*4) = *(const ushort4*)(phiqs + row*136 + c4);
  }
}

// ================= k_main (MFMA): local window + combine =================
__global__ __launch_bounds__(256, 2) void k_main(const float* __restrict__ qry,
                                                 const float* __restrict__ key,
                                                 const float* __restrict__ val,
                                                 float* __restrict__ ws,
                                                 float* __restrict__ out){
  // one phase-overlaid buffer (u16 offsets, all rows 16B-aligned):
  //  phase1: kh @0 [96][72], kl @6912 [96][72], phik @13824 [96][136]   (end 26880)
  //  phase2/3: cjh @0 [64][136], cjl @8704, vt @17408 [64][104], vtl @24064
  __shared__ __align__(16) u16 buf[30720];   // 61440 B
  u16* khs  = buf;
  u16* kls  = buf + 6912;
  u16* phik = buf + 13824;
  u16* cjh  = buf;
  u16* cjl  = buf + 8704;
  u16* vt   = buf + 17408;
  u16* vtl  = buf + 24064;

  const int tid = threadIdx.x;
  const int wave = tid >> 6, l = tid & 63;
  const int g = l >> 4, r16 = l & 15;
  const int qt = blockIdx.x, combo = blockIdx.y;
  const int c = combo >> 5, b = (combo >> 3) & 3, h = combo & 7;
  const int s_base = qt*64 - 16;

  // ---- phase 0: stage k (hi/lo) + phi_k window into LDS; v into regs (T14 split)
  const u16* phikg = ((const u16*)(ws + WS_PHIK)) + (size_t)combo*1056*128;
  float4 vreg[6];
  #pragma unroll
  for(int i=0;i<6;i++){
    int flat = tid + 256*i;
    int j = flat >> 4, e4 = (flat & 15)*4;
    int s = s_base + j;
    float4 u = {0.f,0.f,0.f,0.f};
    float4 w4 = {0.f,0.f,0.f,0.f};
    if(s >= 0){
      u  = *(const float4*)(key + (((size_t)b*4096 + s)*8 + h)*64 + e4);
      w4 = *(const float4*)(val + (((size_t)b*4096 + s)*8 + h)*64 + e4);
    }
    vreg[i] = w4;
    ushort4 hh, ll;
    hh.x = f2b(u.x); ll.x = f2b(u.x - b2f(hh.x));
    hh.y = f2b(u.y); ll.y = f2b(u.y - b2f(hh.y));
    hh.z = f2b(u.z); ll.z = f2b(u.z - b2f(hh.z));
    hh.w = f2b(u.w); ll.w = f2b(u.w - b2f(hh.w));
    *(ushort4*)(khs + j*72 + e4) = hh;
    *(ushort4*)(kls + j*72 + e4) = ll;
  }
  #pragma unroll
  for(int i=0;i<12;i++){
    int flat = tid + 256*i;
    int j = flat >> 5, c4 = (flat & 31)*4;
    int s = s_base + j;
    ushort4 p = {0,0,0,0};
    if(s >= 0) p = *(const ushort4*)(phikg + (size_t)s*128 + c4);
    *(ushort4*)(phik + j*136 + c4) = p;
  }
  // wave-private A-fragments: q rows (hi/lo split) + phi_q rows
  const int qrow = qt*64 + wave*16 + r16;    // this lane's A-row (query)
  const float* qr = qry + (((size_t)b*4096 + (c*1024 + qrow))*8 + h)*64;
  short8 ah[2], al[2];
  #pragma unroll
  for(int ks=0;ks<2;ks++){
    float4 u0 = *(const float4*)(qr + ks*32 + g*8);
    float4 u1 = *(const float4*)(qr + ks*32 + g*8 + 4);
    float x[8] = {u0.x,u0.y,u0.z,u0.w,u1.x,u1.y,u1.z,u1.w};
    #pragma unroll
    for(int jj=0;jj<8;jj++){
      u16 hb = f2b(x[jj]);
      ah[ks][jj] = (short)hb;
      al[ks][jj] = (short)f2b(x[jj] - b2f(hb));
    }
  }
  const u16* phiqg = ((const u16*)(ws + WS_PHIQ)) + ((size_t)combo*1024 + qt*64)*128;
  short8 pa[4];
  #pragma unroll
  for(int ks=0;ks<4;ks++)
    pa[ks] = *(const short8*)(phiqg + (wave*16 + r16)*128 + ks*32 + g*8);
  // per-query scalars for this lane's 4 C-rows (row = wave*16 + 4g + r)
  float plsr[4], lr1r[4];
  #pragma unroll
  for(int r=0;r<4;r++){
    int row = qt*64 + wave*16 + 4*g + r;
    plsr[r] = ws[WS_PLS + combo*1024 + row];
    lr1r[r] = ws[WS_LR1 + combo*1024 + row];
  }
  __syncthreads();

  // ---- phase 1: S (scores) and D (dots_p) over the full 16x96 stripe
  const f32x4 zero4 = {0.f,0.f,0.f,0.f};
  f32x4 sacc[6], dacc[6];
  #pragma unroll
  for(int j=0;j<6;j++){ sacc[j] = zero4; dacc[j] = zero4; }
  #pragma unroll
  for(int j=0;j<6;j++){
    #pragma unroll
    for(int ks=0;ks<2;ks++){
      short8 kbh = *(const short8*)(khs + (j*16 + r16)*72 + ks*32 + g*8);
      short8 kbl = *(const short8*)(kls + (j*16 + r16)*72 + ks*32 + g*8);
      sacc[j] = __builtin_amdgcn_mfma_f32_16x16x32_bf16(ah[ks], kbh, sacc[j], 0, 0, 0);
      sacc[j] = __builtin_amdgcn_mfma_f32_16x16x32_bf16(al[ks], kbh, sacc[j], 0, 0, 0);
      sacc[j] = __builtin_amdgcn_mfma_f32_16x16x32_bf16(ah[ks], kbl, sacc[j], 0, 0, 0);
    }
    #pragma unroll
    for(int ks=0;ks<4;ks++){
      short8 pb = *(const short8*)(phik + (j*16 + r16)*136 + ks*32 + g*8);
      dacc[j] = __builtin_amdgcn_mfma_f32_16x16x32_bf16(pa[ks], pb, dacc[j], 0, 0, 0);
    }
  }
  __syncthreads();   // all phase-1 LDS reads done; region reused below

  // ---- phase 2: v -> LDS (transposed, hi/lo); in-register softmax/normalizer; cj -> LDS
  #pragma unroll
  for(int i=0;i<6;i++){
    int flat = tid + 256*i;
    int j = flat >> 4, e4 = (flat & 15)*4;
    float4 u = vreg[i];
    u16 h0 = f2b(u.x), h1 = f2b(u.y), h2 = f2b(u.z), h3 = f2b(u.w);
    vt[(e4+0)*104 + j] = h0; vtl[(e4+0)*104 + j] = f2b(u.x - b2f(h0));
    vt[(e4+1)*104 + j] = h1; vtl[(e4+1)*104 + j] = f2b(u.y - b2f(h1));
    vt[(e4+2)*104 + j] = h2; vtl[(e4+2)*104 + j] = f2b(u.z - b2f(h2));
    vt[(e4+3)*104 + j] = h3; vtl[(e4+3)*104 + j] = f2b(u.w - b2f(h3));
  }
  // band mask: C-layout row = 4g+r (query), col = r16 (key within tile j)
  const int rowb = wave*16 + 4*g;
  float m1r[4] = {-1e30f,-1e30f,-1e30f,-1e30f};
  #pragma unroll
  for(int j=0;j<6;j++){
    #pragma unroll
    for(int r=0;r<4;r++){
      int rel = 16*j + r16 - 16 - (rowb + r);
      bool ok = (rel >= -16) && (rel < 16) && (s_base + 16*j + r16 >= 0);
      if(ok) m1r[r] = fmaxf(m1r[r], sacc[j][r]);
    }
  }
  #pragma unroll
  for(int r=0;r<4;r++){
    m1r[r] = fmaxf(m1r[r], __shfl_xor(m1r[r], 1));
    m1r[r] = fmaxf(m1r[r], __shfl_xor(m1r[r], 2));
    m1r[r] = fmaxf(m1r[r], __shfl_xor(m1r[r], 4));
    m1r[r] = fmaxf(m1r[r], __shfl_xor(m1r[r], 8));
  }
  float ser[4] = {0.f,0.f,0.f,0.f}, wpr[4] = {0.f,0.f,0.f,0.f};
  #pragma unroll
  for(int j=0;j<6;j++){
    #pragma unroll
    for(int r=0;r<4;r++){
      int rel = 16*j + r16 - 16 - (rowb + r);
      bool ok = (rel >= -16) && (rel < 16) && (s_base + 16*j + r16 >= 0);
      if(ok){
        ser[r] += __expf(sacc[j][r] - m1r[r]);
        wpr[r] += dacc[j][r];
      }
    }
  }
  #pragma unroll
  for(int r=0;r<4;r++){
    ser[r] += __shfl_xor(ser[r], 1); ser[r] += __shfl_xor(ser[r], 2);
    ser[r] += __shfl_xor(ser[r], 4); ser[r] += __shfl_xor(ser[r], 8);
    wpr[r] += __shfl_xor(wpr[r], 1); wpr[r] += __shfl_xor(wpr[r], 2);
    wpr[r] += __shfl_xor(wpr[r], 4); wpr[r] += __shfl_xor(wpr[r], 8);
  }
  float lnr[4], scr[4];
  #pragma unroll
  for(int r=0;r<4;r++){
    float qk_lse = m1r[r] + __logf(ser[r]);
    float lrem = fmaxf(lr1r[r] - wpr[r], 1e-37f);
    float bb = __logf(lrem) + plsr[r];
    float ln = fmaxf(qk_lse, bb) + log1pf(__expf(-fabsf(qk_lse - bb)));
    lnr[r] = ln;
    scr[r] = __expf(plsr[r] - ln);
  }
  #pragma unroll
  for(int j=0;j<6;j++){
    #pragma unroll
    for(int r=0;r<4;r++){
      int rel = 16*j + r16 - 16 - (rowb + r);
      bool ok = (rel >= -16) && (rel < 16) && (s_base + 16*j + r16 >= 0);
      float cj = ok ? (__expf(sacc[j][r] - lnr[r]) - scr[r]*dacc[j][r]) : 0.f;
      u16 hb = f2b(cj);
      cjh[(rowb + r)*136 + 16*j + r16] = hb;
      cjl[(rowb + r)*136 + 16*j + r16] = f2b(cj - b2f(hb));
    }
  }
  __syncthreads();

  // ---- phase 3: out = cj . v_win (hi/lo split) + scale*lr_v
  f32x4 oacc[4];
  #pragma unroll
  for(int dt=0;dt<4;dt++) oacc[dt] = zero4;
  #pragma unroll
  for(int ks=0;ks<3;ks++){
    short8 ch = *(const short8*)(cjh + (wave*16 + r16)*136 + ks*32 + g*8);
    short8 cl = *(const short8*)(cjl + (wave*16 + r16)*136 + ks*32 + g*8);
    #pragma unroll
    for(int dt=0;dt<4;dt++){
      short8 vbh = *(const short8*)(vt  + (dt*16 + r16)*104 + ks*32 + g*8);
      short8 vbl = *(const short8*)(vtl + (dt*16 + r16)*104 + ks*32 + g*8);
      oacc[dt] = __builtin_amdgcn_mfma_f32_16x16x32_bf16(ch, vbh, oacc[dt], 0, 0, 0);
      oacc[dt] = __builtin_amdgcn_mfma_f32_16x16x32_bf16(cl, vbh, oacc[dt], 0, 0, 0);
      oacc[dt] = __builtin_amdgcn_mfma_f32_16x16x32_bf16(ch, vbl, oacc[dt], 0, 0, 0);
    }
  }
  const u16* lrvg = ((const u16*)(ws + WS_LRV)) + ((size_t)combo*1024 + qt*64)*64;
  #pragma unroll
  for(int r=0;r<4;r++){
    int row = rowb + r;                      // query within 64
    float* ob = out + ((((size_t)b*8 + h)*4096) + (size_t)c*1024 + qt*64 + row)*64;
    #pragma unroll
    for(int dt=0;dt<4;dt++){
      float lv = b2f(lrvg[row*64 + dt*16 + r16]);
      ob[dt*16 + r16] = oacc[dt][r] + scr[r]*lv;
    }
  }
}

extern "C" void kernel_launch(void* const* d_in, const int* in_sizes, int n_in,
                              void* d_out, int out_size, void* d_ws, size_t ws_size,
                              hipStream_t stream){
  (void)in_sizes; (void)n_in; (void)out_size; (void)ws_size;
  const float* q = (const float*)d_in[0];
  const float* k = (const float*)d_in[1];
  const float* v = (const float*)d_in[2];
  const float* p = (const float*)d_in[3];
  float* out = (float*)d_out;
  float* ws = (float*)d_ws;
  hipMemsetAsync(ws + WS_K1, 0, (size_t)(16384 + 1048576)*sizeof(float), stream);
  k_phi <<<dim3(8,128),  256, 0, stream>>>(k, v, p, ws);
  k_q   <<<dim3(16,128), 256, 0, stream>>>(q, p, ws);
  k_main<<<dim3(16,128), 256, 0, stream>>>(q, k, v, ws, out);
}

// Round 9
// 343.247 us; speedup vs baseline: 1.1511x; 1.1218x over previous
//
#include <hip/hip_runtime.h>

typedef unsigned short u16;
typedef unsigned int   u32;
typedef __attribute__((ext_vector_type(8))) short short8;
typedef __attribute__((ext_vector_type(4))) float f32x4;

#define LOGM 4.852030263919617f

// workspace layout (float offsets)
constexpr int WS_PMAX = 0;         // 128 floats (per-combo stabilizer bound, by k_stab)
constexpr int WS_K1   = 2048;      // 128*128 floats (k1sum, atomic-accumulated)
constexpr int WS_KV   = 18432;     // 128*128*64 floats (kv [m][d], atomic-accumulated)
constexpr int WS_PHIK = 1067008;   // u16: 128 combos * 1056 * 128 (phi_k bf16, [s][m])
constexpr int WS_PLS  = 9717760;   // 128*1024 floats
constexpr int WS_LR1  = 9848832;   // 128*1024 floats
constexpr int WS_PHIQ = 9979904;   // u16: 128 * 1024 * 128 (phi_q bf16, [q][m])
constexpr int WS_LRV  = 18368512;  // u16: 128 * 1024 * 64 (lr_v bf16, [q][d])

__device__ __forceinline__ float b2f(u16 u){ union { u32 i; float f; } x; x.i = ((u32)u) << 16; return x.f; }
__device__ __forceinline__ u16 f2b(float f){ union { float f; u32 i; } x; x.f = f; return (u16)((x.i + 0x7fffu + ((x.i >> 16) & 1u)) >> 16); }

// ================= k_stab: per-c proj stabilizer (4 values), once =================
__global__ __launch_bounds__(128) void k_stab(const float* __restrict__ proj,
                                              float* __restrict__ ws){
  __shared__ float red[2];
  const int c = blockIdx.x, tid = threadIdx.x;
  const int wave = tid >> 6, l = tid & 63;
  const float4* pr = (const float4*)(proj + c*8192 + tid*64);
  float pn = 0.f;
  #pragma unroll
  for(int i=0;i<16;i++){ float4 u = pr[i]; pn = fmaf(u.x,u.x,fmaf(u.y,u.y,fmaf(u.z,u.z,fmaf(u.w,u.w,pn)))); }
  #pragma unroll
  for(int o=1;o<64;o<<=1) pn = fmaxf(pn, __shfl_xor(pn, o));
  if(l == 0) red[wave] = pn;
  __syncthreads();
  const float stab = 0.5f * fmaxf(red[0], red[1]);
  if(tid < 32) ws[WS_PMAX + c*32 + tid] = stab;   // all combos with this c
}

// ================= k_phi: logk MFMA -> phi_k -> ws; kv & k1 atomics =================
// grid (4,128): kq block owns tiles {kq, kq+4, kq+8, ...} (s_tile = (kq+4*t0)*64) —
// INTERLEAVED so the phi_k dump tiles (s<1056) spread 4-5 per block instead of 16-vs-0
// (r6 measured occupancy 18.6% < 25% cap: dump-tail imbalance).
// stab read from ws (k_stab) — drops the per-block norm pass + barrier.
// (256,2): kernel needs ~128 VGPR + 64 AGPR; higher bounds spill (r5), m-split adds
// traffic (r8), dbuf+prefetch thrashes L2 (r7). This structure is the measured best.
__global__ __launch_bounds__(256, 2) void k_phi(const float* __restrict__ key,
                                                const float* __restrict__ val,
                                                const float* __restrict__ proj,
                                                float* __restrict__ ws){
  __shared__ __align__(16) u16 phit[128*72];   // [m][key64] bf16, stride 72
  __shared__ __align__(16) u16 vt[64*72];      // [d][key64] bf16, stride 72, col-swizzled
  const int tid = threadIdx.x;
  const int wave = tid >> 6, l = tid & 63;
  const int g = l >> 4, r16 = l & 15;
  const int kq = blockIdx.x, combo = blockIdx.y;
  const int c = combo >> 5, b = (combo >> 3) & 3, h = combo & 7;
  const float* projc = proj + c*8192;
  const float stab = ws[WS_PMAX + combo];

  short8 ph[8][2], pl[8][2];
  #pragma unroll
  for(int mt=0;mt<8;mt++){
    #pragma unroll
    for(int ks=0;ks<2;ks++){
      const float* pb = projc + (mt*16 + r16)*64 + ks*32 + g*8;
      float4 u0 = *(const float4*)pb;
      float4 u1 = *(const float4*)(pb + 4);
      float x[8] = {u0.x,u0.y,u0.z,u0.w,u1.x,u1.y,u1.z,u1.w};
      #pragma unroll
      for(int j=0;j<8;j++){
        u16 hb = f2b(x[j]);
        ph[mt][ks][j] = (short)hb;
        pl[mt][ks][j] = (short)f2b(x[j] - b2f(hb));
      }
    }
  }

  const f32x4 zero4 = {0.f,0.f,0.f,0.f};
  f32x4 kvacc[2][4];
  #pragma unroll
  for(int i=0;i<2;i++)
    #pragma unroll
    for(int j=0;j<4;j++) kvacc[i][j] = zero4;
  float k1p0 = 0.f, k1p1 = 0.f;
  u16* phikg = ((u16*)(ws + WS_PHIK)) + (size_t)combo*1056*128;

  for(int t0=0;t0<16;t0++){
    const int s_tile = (kq + 4*t0)*64;      // interleaved tile map
    const bool dtile = (s_tile < 1056);
    const int sA = s_tile + wave*16 + r16;
    const float* krow = key + (size_t)(b*4096 + sA)*512 + h*64;
    float areg[16];
    #pragma unroll
    for(int ks=0;ks<2;ks++){
      float4 u0 = *(const float4*)(krow + ks*32 + g*8);
      float4 u1 = *(const float4*)(krow + ks*32 + g*8 + 4);
      areg[ks*8+0]=u0.x; areg[ks*8+1]=u0.y; areg[ks*8+2]=u0.z; areg[ks*8+3]=u0.w;
      areg[ks*8+4]=u1.x; areg[ks*8+5]=u1.y; areg[ks*8+6]=u1.z; areg[ks*8+7]=u1.w;
    }
    // issue v loads now; consumed after the MFMA block (latency hidden under compute)
    float4 vreg[4];
    #pragma unroll
    for(int i=0;i<4;i++){
      int flat = tid + 256*i;
      int sv = flat >> 4, d4 = (flat & 15)*4;
      vreg[i] = *(const float4*)(val + (size_t)(b*4096 + s_tile + sv)*512 + h*64 + d4);
    }
    float ksq = 0.f;
    #pragma unroll
    for(int e=0;e<16;e++) ksq = fmaf(areg[e], areg[e], ksq);
    ksq += __shfl_xor(ksq, 16);
    ksq += __shfl_xor(ksq, 32);
    ksq *= 0.5f;
    short8 ah[2], al[2];
    #pragma unroll
    for(int ks=0;ks<2;ks++){
      #pragma unroll
      for(int j=0;j<8;j++){
        float x = areg[ks*8+j];
        u16 hb = f2b(x);
        ah[ks][j] = (short)hb;
        al[ks][j] = (short)f2b(x - b2f(hb));
      }
    }
    f32x4 acc[8];
    #pragma unroll
    for(int mt=0;mt<8;mt++) acc[mt] = zero4;
    #pragma unroll
    for(int ks=0;ks<2;ks++){
      #pragma unroll
      for(int mt=0;mt<8;mt++){
        acc[mt] = __builtin_amdgcn_mfma_f32_16x16x32_bf16(ah[ks], ph[mt][ks], acc[mt], 0, 0, 0);
        acc[mt] = __builtin_amdgcn_mfma_f32_16x16x32_bf16(ah[ks], pl[mt][ks], acc[mt], 0, 0, 0);
        acc[mt] = __builtin_amdgcn_mfma_f32_16x16x32_bf16(al[ks], ph[mt][ks], acc[mt], 0, 0, 0);
      }
    }
    const float kc0 = __shfl(ksq, 4*g + 0);
    const float kc1 = __shfl(ksq, 4*g + 1);
    const float kc2 = __shfl(ksq, 4*g + 2);
    const float kc3 = __shfl(ksq, 4*g + 3);
    const int gs = s_tile + wave*16 + r16;
    #pragma unroll
    for(int mt=0;mt<8;mt++){
      ushort4 pw;
      pw.x = f2b(__expf(acc[mt][0] - kc0 - stab));
      pw.y = f2b(__expf(acc[mt][1] - kc1 - stab));
      pw.z = f2b(__expf(acc[mt][2] - kc2 - stab));
      pw.w = f2b(__expf(acc[mt][3] - kc3 - stab));
      *(ushort4*)(phit + (mt*16 + r16)*72 + wave*16 + 4*g) = pw;
      // direct register->global transpose scatter: rows [s][m], m = mt*16+4g..+3
      if(dtile && gs < 1056)
        *(ushort4*)(phikg + (size_t)gs*128 + mt*16 + 4*g) = pw;
    }
    // vt store, col-swizzled: (d, s) -> d*72 + (s ^ 8*((d>>2)&7))
    #pragma unroll
    for(int i=0;i<4;i++){
      int flat = tid + 256*i;
      int sv = flat >> 4, d4 = (flat & 15)*4;
      float x[4] = {vreg[i].x, vreg[i].y, vreg[i].z, vreg[i].w};
      #pragma unroll
      for(int j=0;j<4;j++){
        int d = d4 + j;
        vt[d*72 + (sv ^ (8*((d>>2)&7)))] = f2b(x[j]);
      }
    }
    __syncthreads();
    #pragma unroll
    for(int ks=0;ks<2;ks++){
      short8 af0 = *(const short8*)(phit + ((2*wave+0)*16 + r16)*72 + ks*32 + g*8);
      short8 af1 = *(const short8*)(phit + ((2*wave+1)*16 + r16)*72 + ks*32 + g*8);
      short8 bf[4];
      #pragma unroll
      for(int dt=0;dt<4;dt++){
        int d = dt*16 + r16;
        int col = (ks*32 + g*8) ^ (8*((d>>2)&7));
        bf[dt] = *(const short8*)(vt + d*72 + col);
      }
      #pragma unroll
      for(int dt=0;dt<4;dt++){
        kvacc[0][dt] = __builtin_amdgcn_mfma_f32_16x16x32_bf16(af0, bf[dt], kvacc[0][dt], 0, 0, 0);
        kvacc[1][dt] = __builtin_amdgcn_mfma_f32_16x16x32_bf16(af1, bf[dt], kvacc[1][dt], 0, 0, 0);
      }
      #pragma unroll
      for(int j=0;j<8;j++){ k1p0 += b2f((u16)af0[j]); k1p1 += b2f((u16)af1[j]); }
    }
    __syncthreads();
  }
  k1p0 += __shfl_xor(k1p0, 16); k1p0 += __shfl_xor(k1p0, 32);
  k1p1 += __shfl_xor(k1p1, 16); k1p1 += __shfl_xor(k1p1, 32);
  if(l < 16){
    atomicAdd(ws + WS_K1 + combo*128 + (2*wave+0)*16 + l, k1p0);
    atomicAdd(ws + WS_K1 + combo*128 + (2*wave+1)*16 + l, k1p1);
  }
  #pragma unroll
  for(int mi=0;mi<2;mi++){
    #pragma unroll
    for(int dt=0;dt<4;dt++){
      #pragma unroll
      for(int rr=0;rr<4;rr++){
        int m = (2*wave+mi)*16 + 4*g + rr;
        int d = dt*16 + r16;
        atomicAdd(ws + WS_KV + (size_t)combo*8192 + m*64 + d, kvacc[mi][dt][rr]);
      }
    }
  }
}

// ================= k_q: logq MFMA -> phi_q/pls/lr1; lr_v = phi_q . kv MFMA =================
__global__ __launch_bounds__(256, 2) void k_q(const float* __restrict__ qry,
                                              const float* __restrict__ proj,
                                              float* __restrict__ ws){
  __shared__ __align__(16) u16 phiqs[64*136];  // [q][m] bf16, stride 136
  __shared__ __align__(16) u16 kvt[64*136];    // [d][m] bf16
  __shared__ float k1s[128];
  const int tid = threadIdx.x;
  const int wave = tid >> 6, l = tid & 63;
  const int g = l >> 4, r16 = l & 15;
  const int qt = blockIdx.x, combo = blockIdx.y;
  const int c = combo >> 5, b = (combo >> 3) & 3, h = combo & 7;
  const float* projc = proj + c*8192;
  const float stab = ws[WS_PMAX + combo];
  if(tid < 128) k1s[tid] = ws[WS_K1 + combo*128 + tid];
  const float* kvg = ws + WS_KV + (size_t)combo*8192;
  #pragma unroll
  for(int i=0;i<8;i++){
    int flat = tid + 256*i;
    int m = flat >> 4, d4 = (flat & 15)*4;
    float4 u = *(const float4*)(kvg + m*64 + d4);
    kvt[(d4+0)*136 + m] = f2b(u.x);
    kvt[(d4+1)*136 + m] = f2b(u.y);
    kvt[(d4+2)*136 + m] = f2b(u.z);
    kvt[(d4+3)*136 + m] = f2b(u.w);
  }
  const int qrow = qt*64 + wave*16 + r16;
  const float* qr = qry + (size_t)(b*4096 + (c*1024 + qrow))*512 + h*64;
  float areg[16];
  #pragma unroll
  for(int ks=0;ks<2;ks++){
    float4 u0 = *(const float4*)(qr + ks*32 + g*8);
    float4 u1 = *(const float4*)(qr + ks*32 + g*8 + 4);
    areg[ks*8+0]=u0.x; areg[ks*8+1]=u0.y; areg[ks*8+2]=u0.z; areg[ks*8+3]=u0.w;
    areg[ks*8+4]=u1.x; areg[ks*8+5]=u1.y; areg[ks*8+6]=u1.z; areg[ks*8+7]=u1.w;
  }
  float qsq = 0.f;
  #pragma unroll
  for(int e=0;e<16;e++) qsq = fmaf(areg[e], areg[e], qsq);
  qsq += __shfl_xor(qsq, 16);
  qsq += __shfl_xor(qsq, 32);
  qsq *= 0.5f;
  short8 ah[2], al[2];
  #pragma unroll
  for(int ks=0;ks<2;ks++){
    #pragma unroll
    for(int j=0;j<8;j++){
      float x = areg[ks*8+j];
      u16 hb = f2b(x);
      ah[ks][j] = (short)hb;
      al[ks][j] = (short)f2b(x - b2f(hb));
    }
  }
  const f32x4 zero4 = {0.f,0.f,0.f,0.f};
  f32x4 acc[8];
  #pragma unroll
  for(int mt=0;mt<8;mt++) acc[mt] = zero4;
  #pragma unroll
  for(int ks=0;ks<2;ks++){
    #pragma unroll
    for(int mt=0;mt<8;mt++){
      const float* pb = projc + (mt*16 + r16)*64 + ks*32 + g*8;
      float4 u0 = *(const float4*)pb;
      float4 u1 = *(const float4*)(pb + 4);
      float x[8] = {u0.x,u0.y,u0.z,u0.w,u1.x,u1.y,u1.z,u1.w};
      short8 pph, ppl;
      #pragma unroll
      for(int j=0;j<8;j++){
        u16 hb = f2b(x[j]);
        pph[j] = (short)hb;
        ppl[j] = (short)f2b(x[j] - b2f(hb));
      }
      acc[mt] = __builtin_amdgcn_mfma_f32_16x16x32_bf16(ah[ks], pph, acc[mt], 0, 0, 0);
      acc[mt] = __builtin_amdgcn_mfma_f32_16x16x32_bf16(ah[ks], ppl, acc[mt], 0, 0, 0);
      acc[mt] = __builtin_amdgcn_mfma_f32_16x16x32_bf16(al[ks], pph, acc[mt], 0, 0, 0);
    }
  }
  float qsr[4];
  #pragma unroll
  for(int r=0;r<4;r++) qsr[r] = __shfl(qsq, 4*g + r);
  float amax[4];
  #pragma unroll
  for(int r=0;r<4;r++){
    float m = -3e38f;
    #pragma unroll
    for(int mt=0;mt<8;mt++) m = fmaxf(m, acc[mt][r]);
    m = fmaxf(m, __shfl_xor(m, 1));
    m = fmaxf(m, __shfl_xor(m, 2));
    m = fmaxf(m, __shfl_xor(m, 4));
    m = fmaxf(m, __shfl_xor(m, 8));
    amax[r] = m;
  }
  float lrp[4] = {0.f,0.f,0.f,0.f};
  #pragma unroll
  for(int mt=0;mt<8;mt++){
    const float k1v = k1s[mt*16 + r16];
    #pragma unroll
    for(int r=0;r<4;r++){
      float phv = __expf(acc[mt][r] - amax[r]);
      phiqs[(wave*16 + 4*g + r)*136 + mt*16 + r16] = f2b(phv);
      lrp[r] = fmaf(phv, k1v, lrp[r]);
    }
  }
  #pragma unroll
  for(int r=0;r<4;r++){
    lrp[r] += __shfl_xor(lrp[r], 1);
    lrp[r] += __shfl_xor(lrp[r], 2);
    lrp[r] += __shfl_xor(lrp[r], 4);
    lrp[r] += __shfl_xor(lrp[r], 8);
  }
  if(r16 == 0){
    #pragma unroll
    for(int r=0;r<4;r++){
      int row = qt*64 + wave*16 + 4*g + r;
      ws[WS_PLS + combo*1024 + row] = amax[r] - qsr[r] + stab - LOGM;
      ws[WS_LR1 + combo*1024 + row] = lrp[r];
    }
  }
  __syncthreads();
  f32x4 lacc[4];
  #pragma unroll
  for(int dt=0;dt<4;dt++) lacc[dt] = zero4;
  #pragma unroll
  for(int ks=0;ks<4;ks++){
    short8 a = *(const short8*)(phiqs + (wave*16 + r16)*136 + ks*32 + g*8);
    #pragma unroll
    for(int dt=0;dt<4;dt++){
      short8 bfr = *(const short8*)(kvt + (dt*16 + r16)*136 + ks*32 + g*8);
      lacc[dt] = __builtin_amdgcn_mfma_f32_16x16x32_bf16(a, bfr, lacc[dt], 0, 0, 0);
    }
  }
  u16* lrvg = ((u16*)(ws + WS_LRV)) + ((size_t)combo*1024 + qt*64)*64;
  #pragma unroll
  for(int dt=0;dt<4;dt++){
    #pragma unroll
    for(int r=0;r<4;r++)
      lrvg[(wave*16 + 4*g + r)*64 + dt*16 + r16] = f2b(lacc[dt][r]);
  }
  u16* phiqg = ((u16*)(ws + WS_PHIQ)) + ((size_t)combo*1024 + qt*64)*128;
  #pragma unroll
  for(int i=0;i<8;i++){
    int flat = tid + 256*i;
    int row = flat >> 5, c4 = (flat & 31)*4;
    *(ushort4*)(phiqg + flat*4) = *(const ushort4*)(phiqs + row*136 + c4);
  }
}

// ================= k_main (MFMA): local window + combine =================
__global__ __launch_bounds__(256, 2) void k_main(const float* __restrict__ qry,
                                                 const float* __restrict__ key,
                                                 const float* __restrict__ val,
                                                 float* __restrict__ ws,
                                                 float* __restrict__ out){
  // one phase-overlaid buffer (u16 offsets, all rows 16B-aligned):
  //  phase1: kh @0 [96][72], kl @6912 [96][72], phik @13824 [96][136]   (end 26880)
  //  phase2/3: cjh @0 [64][136], cjl @8704, vt @17408 [64][104], vtl @24064
  __shared__ __align__(16) u16 buf[30720];   // 61440 B
  u16* khs  = buf;
  u16* kls  = buf + 6912;
  u16* phik = buf + 13824;
  u16* cjh  = buf;
  u16* cjl  = buf + 8704;
  u16* vt   = buf + 17408;
  u16* vtl  = buf + 24064;

  const int tid = threadIdx.x;
  const int wave = tid >> 6, l = tid & 63;
  const int g = l >> 4, r16 = l & 15;
  const int qt = blockIdx.x, combo = blockIdx.y;
  const int c = combo >> 5, b = (combo >> 3) & 3, h = combo & 7;
  const int s_base = qt*64 - 16;

  // ---- phase 0: stage k (hi/lo) + phi_k window into LDS; v into regs (T14 split)
  const u16* phikg = ((const u16*)(ws + WS_PHIK)) + (size_t)combo*1056*128;
  float4 vreg[6];
  #pragma unroll
  for(int i=0;i<6;i++){
    int flat = tid + 256*i;
    int j = flat >> 4, e4 = (flat & 15)*4;
    int s = s_base + j;
    float4 u = {0.f,0.f,0.f,0.f};
    float4 w4 = {0.f,0.f,0.f,0.f};
    if(s >= 0){
      u  = *(const float4*)(key + (((size_t)b*4096 + s)*8 + h)*64 + e4);
      w4 = *(const float4*)(val + (((size_t)b*4096 + s)*8 + h)*64 + e4);
    }
    vreg[i] = w4;
    ushort4 hh, ll;
    hh.x = f2b(u.x); ll.x = f2b(u.x - b2f(hh.x));
    hh.y = f2b(u.y); ll.y = f2b(u.y - b2f(hh.y));
    hh.z = f2b(u.z); ll.z = f2b(u.z - b2f(hh.z));
    hh.w = f2b(u.w); ll.w = f2b(u.w - b2f(hh.w));
    *(ushort4*)(khs + j*72 + e4) = hh;
    *(ushort4*)(kls + j*72 + e4) = ll;
  }
  #pragma unroll
  for(int i=0;i<12;i++){
    int flat = tid + 256*i;
    int j = flat >> 5, c4 = (flat & 31)*4;
    int s = s_base + j;
    ushort4 p = {0,0,0,0};
    if(s >= 0) p = *(const ushort4*)(phikg + (size_t)s*128 + c4);
    *(ushort4*)(phik + j*136 + c4) = p;
  }
  // wave-private A-fragments: q rows (hi/lo split) + phi_q rows
  const int qrow = qt*64 + wave*16 + r16;    // this lane's A-row (query)
  const float* qr = qry + (((size_t)b*4096 + (c*1024 + qrow))*8 + h)*64;
  short8 ah[2], al[2];
  #pragma unroll
  for(int ks=0;ks<2;ks++){
    float4 u0 = *(const float4*)(qr + ks*32 + g*8);
    float4 u1 = *(const float4*)(qr + ks*32 + g*8 + 4);
    float x[8] = {u0.x,u0.y,u0.z,u0.w,u1.x,u1.y,u1.z,u1.w};
    #pragma unroll
    for(int jj=0;jj<8;jj++){
      u16 hb = f2b(x[jj]);
      ah[ks][jj] = (short)hb;
      al[ks][jj] = (short)f2b(x[jj] - b2f(hb));
    }
  }
  const u16* phiqg = ((const u16*)(ws + WS_PHIQ)) + ((size_t)combo*1024 + qt*64)*128;
  short8 pa[4];
  #pragma unroll
  for(int ks=0;ks<4;ks++)
    pa[ks] = *(const short8*)(phiqg + (wave*16 + r16)*128 + ks*32 + g*8);
  // per-query scalars for this lane's 4 C-rows (row = wave*16 + 4g + r)
  float plsr[4], lr1r[4];
  #pragma unroll
  for(int r=0;r<4;r++){
    int row = qt*64 + wave*16 + 4*g + r;
    plsr[r] = ws[WS_PLS + combo*1024 + row];
    lr1r[r] = ws[WS_LR1 + combo*1024 + row];
  }
  __syncthreads();

  // ---- phase 1: S (scores) and D (dots_p) over the full 16x96 stripe
  const f32x4 zero4 = {0.f,0.f,0.f,0.f};
  f32x4 sacc[6], dacc[6];
  #pragma unroll
  for(int j=0;j<6;j++){ sacc[j] = zero4; dacc[j] = zero4; }
  #pragma unroll
  for(int j=0;j<6;j++){
    #pragma unroll
    for(int ks=0;ks<2;ks++){
      short8 kbh = *(const short8*)(khs + (j*16 + r16)*72 + ks*32 + g*8);
      short8 kbl = *(const short8*)(kls + (j*16 + r16)*72 + ks*32 + g*8);
      sacc[j] = __builtin_amdgcn_mfma_f32_16x16x32_bf16(ah[ks], kbh, sacc[j], 0, 0, 0);
      sacc[j] = __builtin_amdgcn_mfma_f32_16x16x32_bf16(al[ks], kbh, sacc[j], 0, 0, 0);
      sacc[j] = __builtin_amdgcn_mfma_f32_16x16x32_bf16(ah[ks], kbl, sacc[j], 0, 0, 0);
    }
    #pragma unroll
    for(int ks=0;ks<4;ks++){
      short8 pb = *(const short8*)(phik + (j*16 + r16)*136 + ks*32 + g*8);
      dacc[j] = __builtin_amdgcn_mfma_f32_16x16x32_bf16(pa[ks], pb, dacc[j], 0, 0, 0);
    }
  }
  __syncthreads();   // all phase-1 LDS reads done; region reused below

  // ---- phase 2: v -> LDS (transposed, hi/lo); in-register softmax/normalizer; cj -> LDS
  #pragma unroll
  for(int i=0;i<6;i++){
    int flat = tid + 256*i;
    int j = flat >> 4, e4 = (flat & 15)*4;
    float4 u = vreg[i];
    u16 h0 = f2b(u.x), h1 = f2b(u.y), h2 = f2b(u.z), h3 = f2b(u.w);
    vt[(e4+0)*104 + j] = h0; vtl[(e4+0)*104 + j] = f2b(u.x - b2f(h0));
    vt[(e4+1)*104 + j] = h1; vtl[(e4+1)*104 + j] = f2b(u.y - b2f(h1));
    vt[(e4+2)*104 + j] = h2; vtl[(e4+2)*104 + j] = f2b(u.z - b2f(h2));
    vt[(e4+3)*104 + j] = h3; vtl[(e4+3)*104 + j] = f2b(u.w - b2f(h3));
  }
  // band mask: C-layout row = 4g+r (query), col = r16 (key within tile j)
  const int rowb = wave*16 + 4*g;
  float m1r[4] = {-1e30f,-1e30f,-1e30f,-1e30f};
  #pragma unroll
  for(int j=0;j<6;j++){
    #pragma unroll
    for(int r=0;r<4;r++){
      int rel = 16*j + r16 - 16 - (rowb + r);
      bool ok = (rel >= -16) && (rel < 16) && (s_base + 16*j + r16 >= 0);
      if(ok) m1r[r] = fmaxf(m1r[r], sacc[j][r]);
    }
  }
  #pragma unroll
  for(int r=0;r<4;r++){
    m1r[r] = fmaxf(m1r[r], __shfl_xor(m1r[r], 1));
    m1r[r] = fmaxf(m1r[r], __shfl_xor(m1r[r], 2));
    m1r[r] = fmaxf(m1r[r], __shfl_xor(m1r[r], 4));
    m1r[r] = fmaxf(m1r[r], __shfl_xor(m1r[r], 8));
  }
  float ser[4] = {0.f,0.f,0.f,0.f}, wpr[4] = {0.f,0.f,0.f,0.f};
  #pragma unroll
  for(int j=0;j<6;j++){
    #pragma unroll
    for(int r=0;r<4;r++){
      int rel = 16*j + r16 - 16 - (rowb + r);
      bool ok = (rel >= -16) && (rel < 16) && (s_base + 16*j + r16 >= 0);
      if(ok){
        ser[r] += __expf(sacc[j][r] - m1r[r]);
        wpr[r] += dacc[j][r];
      }
    }
  }
  #pragma unroll
  for(int r=0;r<4;r++){
    ser[r] += __shfl_xor(ser[r], 1); ser[r] += __shfl_xor(ser[r], 2);
    ser[r] += __shfl_xor(ser[r], 4); ser[r] += __shfl_xor(ser[r], 8);
    wpr[r] += __shfl_xor(wpr[r], 1); wpr[r] += __shfl_xor(wpr[r], 2);
    wpr[r] += __shfl_xor(wpr[r], 4); wpr[r] += __shfl_xor(wpr[r], 8);
  }
  float lnr[4], scr[4];
  #pragma unroll
  for(int r=0;r<4;r++){
    float qk_lse = m1r[r] + __logf(ser[r]);
    float lrem = fmaxf(lr1r[r] - wpr[r], 1e-37f);
    float bb = __logf(lrem) + plsr[r];
    float ln = fmaxf(qk_lse, bb) + log1pf(__expf(-fabsf(qk_lse - bb)));
    lnr[r] = ln;
    scr[r] = __expf(plsr[r] - ln);
  }
  #pragma unroll
  for(int j=0;j<6;j++){
    #pragma unroll
    for(int r=0;r<4;r++){
      int rel = 16*j + r16 - 16 - (rowb + r);
      bool ok = (rel >= -16) && (rel < 16) && (s_base + 16*j + r16 >= 0);
      float cj = ok ? (__expf(sacc[j][r] - lnr[r]) - scr[r]*dacc[j][r]) : 0.f;
      u16 hb = f2b(cj);
      cjh[(rowb + r)*136 + 16*j + r16] = hb;
      cjl[(rowb + r)*136 + 16*j + r16] = f2b(cj - b2f(hb));
    }
  }
  __syncthreads();

  // ---- phase 3: out = cj . v_win (hi/lo split) + scale*lr_v
  f32x4 oacc[4];
  #pragma unroll
  for(int dt=0;dt<4;dt++) oacc[dt] = zero4;
  #pragma unroll
  for(int ks=0;ks<3;ks++){
    short8 ch = *(const short8*)(cjh + (wave*16 + r16)*136 + ks*32 + g*8);
    short8 cl = *(const short8*)(cjl + (wave*16 + r16)*136 + ks*32 + g*8);
    #pragma unroll
    for(int dt=0;dt<4;dt++){
      short8 vbh = *(const short8*)(vt  + (dt*16 + r16)*104 + ks*32 + g*8);
      short8 vbl = *(const short8*)(vtl + (dt*16 + r16)*104 + ks*32 + g*8);
      oacc[dt] = __builtin_amdgcn_mfma_f32_16x16x32_bf16(ch, vbh, oacc[dt], 0, 0, 0);
      oacc[dt] = __builtin_amdgcn_mfma_f32_16x16x32_bf16(cl, vbh, oacc[dt], 0, 0, 0);
      oacc[dt] = __builtin_amdgcn_mfma_f32_16x16x32_bf16(ch, vbl, oacc[dt], 0, 0, 0);
    }
  }
  const u16* lrvg = ((const u16*)(ws + WS_LRV)) + ((size_t)combo*1024 + qt*64)*64;
  #pragma unroll
  for(int r=0;r<4;r++){
    int row = rowb + r;                      // query within 64
    float* ob = out + ((((size_t)b*8 + h)*4096) + (size_t)c*1024 + qt*64 + row)*64;
    #pragma unroll
    for(int dt=0;dt<4;dt++){
      float lv = b2f(lrvg[row*64 + dt*16 + r16]);
      ob[dt*16 + r16] = oacc[dt][r] + scr[r]*lv;
    }
  }
}

extern "C" void kernel_launch(void* const* d_in, const int* in_sizes, int n_in,
                              void* d_out, int out_size, void* d_ws, size_t ws_size,
                              hipStream_t stream){
  (void)in_sizes; (void)n_in; (void)out_size; (void)ws_size;
  const float* q = (const float*)d_in[0];
  const float* k = (const float*)d_in[1];
  const float* v = (const float*)d_in[2];
  const float* p = (const float*)d_in[3];
  float* out = (float*)d_out;
  float* ws = (float*)d_ws;
  hipMemsetAsync(ws + WS_K1, 0, (size_t)(16384 + 1048576)*sizeof(float), stream);
  k_stab<<<dim3(4),      128, 0, stream>>>(p, ws);
  k_phi <<<dim3(4,128),  256, 0, stream>>>(k, v, p, ws);
  k_q   <<<dim3(16,128), 256, 0, stream>>>(q, p, ws);
  k_main<<<dim3(16,128), 256, 0, stream>>>(q, k, v, ws, out);
}

// Round 10
// 324.057 us; speedup vs baseline: 1.2193x; 1.0592x over previous
//
#include <hip/hip_runtime.h>

typedef unsigned short u16;
typedef unsigned int   u32;
typedef __attribute__((ext_vector_type(8))) short short8;
typedef __attribute__((ext_vector_type(4))) float f32x4;

#define LOGM 4.852030263919617f

// workspace layout (float offsets)
constexpr int WS_PMAX = 0;         // 128 floats (per-combo stabilizer bound, by k_stab)
constexpr int WS_K1   = 2048;      // 128*128 floats (k1sum, atomic-accumulated)
constexpr int WS_KV   = 18432;     // 128*128*64 floats (kv [m][d], atomic-accumulated)
constexpr int WS_PHIK = 1067008;   // u16: 128 combos * 1056 * 128 (phi_k bf16, [s][m])

__device__ __forceinline__ float b2f(u16 u){ union { u32 i; float f; } x; x.i = ((u32)u) << 16; return x.f; }
__device__ __forceinline__ u16 f2b(float f){ union { float f; u32 i; } x; x.f = f; return (u16)((x.i + 0x7fffu + ((x.i >> 16) & 1u)) >> 16); }

// ================= k_stab: per-c proj stabilizer (4 values), once =================
__global__ __launch_bounds__(128) void k_stab(const float* __restrict__ proj,
                                              float* __restrict__ ws){
  __shared__ float red[2];
  const int c = blockIdx.x, tid = threadIdx.x;
  const int wave = tid >> 6, l = tid & 63;
  const float4* pr = (const float4*)(proj + c*8192 + tid*64);
  float pn = 0.f;
  #pragma unroll
  for(int i=0;i<16;i++){ float4 u = pr[i]; pn = fmaf(u.x,u.x,fmaf(u.y,u.y,fmaf(u.z,u.z,fmaf(u.w,u.w,pn)))); }
  #pragma unroll
  for(int o=1;o<64;o<<=1) pn = fmaxf(pn, __shfl_xor(pn, o));
  if(l == 0) red[wave] = pn;
  __syncthreads();
  const float stab = 0.5f * fmaxf(red[0], red[1]);
  if(tid < 32) ws[WS_PMAX + c*32 + tid] = stab;   // all combos with this c
}

// ================= k_phi: logk MFMA -> phi_k -> ws; kv & k1 atomics =================
// (r9 verified: interleaved tile map + hoisted stab; 122 us)
__global__ __launch_bounds__(256, 2) void k_phi(const float* __restrict__ key,
                                                const float* __restrict__ val,
                                                const float* __restrict__ proj,
                                                float* __restrict__ ws){
  __shared__ __align__(16) u16 phit[128*72];   // [m][key64] bf16, stride 72
  __shared__ __align__(16) u16 vt[64*72];      // [d][key64] bf16, stride 72, col-swizzled
  const int tid = threadIdx.x;
  const int wave = tid >> 6, l = tid & 63;
  const int g = l >> 4, r16 = l & 15;
  const int kq = blockIdx.x, combo = blockIdx.y;
  const int c = combo >> 5, b = (combo >> 3) & 3, h = combo & 7;
  const float* projc = proj + c*8192;
  const float stab = ws[WS_PMAX + combo];

  short8 ph[8][2], pl[8][2];
  #pragma unroll
  for(int mt=0;mt<8;mt++){
    #pragma unroll
    for(int ks=0;ks<2;ks++){
      const float* pb = projc + (mt*16 + r16)*64 + ks*32 + g*8;
      float4 u0 = *(const float4*)pb;
      float4 u1 = *(const float4*)(pb + 4);
      float x[8] = {u0.x,u0.y,u0.z,u0.w,u1.x,u1.y,u1.z,u1.w};
      #pragma unroll
      for(int j=0;j<8;j++){
        u16 hb = f2b(x[j]);
        ph[mt][ks][j] = (short)hb;
        pl[mt][ks][j] = (short)f2b(x[j] - b2f(hb));
      }
    }
  }

  const f32x4 zero4 = {0.f,0.f,0.f,0.f};
  f32x4 kvacc[2][4];
  #pragma unroll
  for(int i=0;i<2;i++)
    #pragma unroll
    for(int j=0;j<4;j++) kvacc[i][j] = zero4;
  float k1p0 = 0.f, k1p1 = 0.f;
  u16* phikg = ((u16*)(ws + WS_PHIK)) + (size_t)combo*1056*128;

  for(int t0=0;t0<16;t0++){
    const int s_tile = (kq + 4*t0)*64;      // interleaved tile map
    const bool dtile = (s_tile < 1056);
    const int sA = s_tile + wave*16 + r16;
    const float* krow = key + (size_t)(b*4096 + sA)*512 + h*64;
    float areg[16];
    #pragma unroll
    for(int ks=0;ks<2;ks++){
      float4 u0 = *(const float4*)(krow + ks*32 + g*8);
      float4 u1 = *(const float4*)(krow + ks*32 + g*8 + 4);
      areg[ks*8+0]=u0.x; areg[ks*8+1]=u0.y; areg[ks*8+2]=u0.z; areg[ks*8+3]=u0.w;
      areg[ks*8+4]=u1.x; areg[ks*8+5]=u1.y; areg[ks*8+6]=u1.z; areg[ks*8+7]=u1.w;
    }
    float4 vreg[4];
    #pragma unroll
    for(int i=0;i<4;i++){
      int flat = tid + 256*i;
      int sv = flat >> 4, d4 = (flat & 15)*4;
      vreg[i] = *(const float4*)(val + (size_t)(b*4096 + s_tile + sv)*512 + h*64 + d4);
    }
    float ksq = 0.f;
    #pragma unroll
    for(int e=0;e<16;e++) ksq = fmaf(areg[e], areg[e], ksq);
    ksq += __shfl_xor(ksq, 16);
    ksq += __shfl_xor(ksq, 32);
    ksq *= 0.5f;
    short8 ah[2], al[2];
    #pragma unroll
    for(int ks=0;ks<2;ks++){
      #pragma unroll
      for(int j=0;j<8;j++){
        float x = areg[ks*8+j];
        u16 hb = f2b(x);
        ah[ks][j] = (short)hb;
        al[ks][j] = (short)f2b(x - b2f(hb));
      }
    }
    f32x4 acc[8];
    #pragma unroll
    for(int mt=0;mt<8;mt++) acc[mt] = zero4;
    #pragma unroll
    for(int ks=0;ks<2;ks++){
      #pragma unroll
      for(int mt=0;mt<8;mt++){
        acc[mt] = __builtin_amdgcn_mfma_f32_16x16x32_bf16(ah[ks], ph[mt][ks], acc[mt], 0, 0, 0);
        acc[mt] = __builtin_amdgcn_mfma_f32_16x16x32_bf16(ah[ks], pl[mt][ks], acc[mt], 0, 0, 0);
        acc[mt] = __builtin_amdgcn_mfma_f32_16x16x32_bf16(al[ks], ph[mt][ks], acc[mt], 0, 0, 0);
      }
    }
    const float kc0 = __shfl(ksq, 4*g + 0);
    const float kc1 = __shfl(ksq, 4*g + 1);
    const float kc2 = __shfl(ksq, 4*g + 2);
    const float kc3 = __shfl(ksq, 4*g + 3);
    const int gs = s_tile + wave*16 + r16;
    #pragma unroll
    for(int mt=0;mt<8;mt++){
      ushort4 pw;
      pw.x = f2b(__expf(acc[mt][0] - kc0 - stab));
      pw.y = f2b(__expf(acc[mt][1] - kc1 - stab));
      pw.z = f2b(__expf(acc[mt][2] - kc2 - stab));
      pw.w = f2b(__expf(acc[mt][3] - kc3 - stab));
      *(ushort4*)(phit + (mt*16 + r16)*72 + wave*16 + 4*g) = pw;
      if(dtile && gs < 1056)
        *(ushort4*)(phikg + (size_t)gs*128 + mt*16 + 4*g) = pw;
    }
    #pragma unroll
    for(int i=0;i<4;i++){
      int flat = tid + 256*i;
      int sv = flat >> 4, d4 = (flat & 15)*4;
      float x[4] = {vreg[i].x, vreg[i].y, vreg[i].z, vreg[i].w};
      #pragma unroll
      for(int j=0;j<4;j++){
        int d = d4 + j;
        vt[d*72 + (sv ^ (8*((d>>2)&7)))] = f2b(x[j]);
      }
    }
    __syncthreads();
    #pragma unroll
    for(int ks=0;ks<2;ks++){
      short8 af0 = *(const short8*)(phit + ((2*wave+0)*16 + r16)*72 + ks*32 + g*8);
      short8 af1 = *(const short8*)(phit + ((2*wave+1)*16 + r16)*72 + ks*32 + g*8);
      short8 bf[4];
      #pragma unroll
      for(int dt=0;dt<4;dt++){
        int d = dt*16 + r16;
        int col = (ks*32 + g*8) ^ (8*((d>>2)&7));
        bf[dt] = *(const short8*)(vt + d*72 + col);
      }
      #pragma unroll
      for(int dt=0;dt<4;dt++){
        kvacc[0][dt] = __builtin_amdgcn_mfma_f32_16x16x32_bf16(af0, bf[dt], kvacc[0][dt], 0, 0, 0);
        kvacc[1][dt] = __builtin_amdgcn_mfma_f32_16x16x32_bf16(af1, bf[dt], kvacc[1][dt], 0, 0, 0);
      }
      #pragma unroll
      for(int j=0;j<8;j++){ k1p0 += b2f((u16)af0[j]); k1p1 += b2f((u16)af1[j]); }
    }
    __syncthreads();
  }
  k1p0 += __shfl_xor(k1p0, 16); k1p0 += __shfl_xor(k1p0, 32);
  k1p1 += __shfl_xor(k1p1, 16); k1p1 += __shfl_xor(k1p1, 32);
  if(l < 16){
    atomicAdd(ws + WS_K1 + combo*128 + (2*wave+0)*16 + l, k1p0);
    atomicAdd(ws + WS_K1 + combo*128 + (2*wave+1)*16 + l, k1p1);
  }
  #pragma unroll
  for(int mi=0;mi<2;mi++){
    #pragma unroll
    for(int dt=0;dt<4;dt++){
      #pragma unroll
      for(int rr=0;rr<4;rr++){
        int m = (2*wave+mi)*16 + 4*g + rr;
        int d = dt*16 + r16;
        atomicAdd(ws + WS_KV + (size_t)combo*8192 + m*64 + d, kvacc[mi][dt][rr]);
      }
    }
  }
}

// ================= k_qm: fused k_q + k_main =================
// Phase A (k_q): logq MFMA -> phi_q (LDS) / pls,lr1 (regs, uniform per 16-lane
// group) ; lr_v = phi_q . kv MFMA kept in f32 regs (lacc).
// Phase B (k_main): window scores + dots_p + combine, reusing ah/al (q frags),
// pa (phi_q frags), plsr/lr1r, lacc from registers — no WS_PHIQ/LRV/PLS/LR1
// round trips, q loaded once. LDS peak 61440 B (2 blocks/CU, unchanged cap).
__global__ __launch_bounds__(256, 2) void k_qm(const float* __restrict__ qry,
                                               const float* __restrict__ key,
                                               const float* __restrict__ val,
                                               const float* __restrict__ proj,
                                               float* __restrict__ ws,
                                               float* __restrict__ out){
  __shared__ __align__(16) u16 buf[30720];   // 61440 B
  // phase A layout
  u16* kvtA   = buf;            // [d][m] stride 136 (8704 u16)
  u16* phiqsA = buf + 8704;     // [q][m] stride 136 (8704 u16)
  float* k1s  = (float*)(buf + 17408);   // 128 floats (256 u16)
  // phase B layout (overlays; all phase-A reads complete before reuse)
  u16* khs  = buf;              // [96][72]
  u16* kls  = buf + 6912;
  u16* phik = buf + 13824;      // [96][136]
  u16* cjh  = buf;              // [64][136]
  u16* cjl  = buf + 8704;
  u16* vt   = buf + 17408;      // [64][104]
  u16* vtl  = buf + 24064;

  const int tid = threadIdx.x;
  const int wave = tid >> 6, l = tid & 63;
  const int g = l >> 4, r16 = l & 15;
  const int qt = blockIdx.x, combo = blockIdx.y;
  const int c = combo >> 5, b = (combo >> 3) & 3, h = combo & 7;
  const int s_base = qt*64 - 16;
  const float* projc = proj + c*8192;
  const float stab = ws[WS_PMAX + combo];
  const f32x4 zero4 = {0.f,0.f,0.f,0.f};

  // ---- A0: k1s + kv -> LDS (transposed bf16)
  if(tid < 128) k1s[tid] = ws[WS_K1 + combo*128 + tid];
  const float* kvg = ws + WS_KV + (size_t)combo*8192;
  #pragma unroll
  for(int i=0;i<8;i++){
    int flat = tid + 256*i;
    int m = flat >> 4, d4 = (flat & 15)*4;
    float4 u = *(const float4*)(kvg + m*64 + d4);
    kvtA[(d4+0)*136 + m] = f2b(u.x);
    kvtA[(d4+1)*136 + m] = f2b(u.y);
    kvtA[(d4+2)*136 + m] = f2b(u.z);
    kvtA[(d4+3)*136 + m] = f2b(u.w);
  }
  // q fragments (hi/lo) — used by BOTH logq (phase A) and scores (phase B)
  const int qrow = qt*64 + wave*16 + r16;
  const float* qr = qry + (size_t)(b*4096 + (c*1024 + qrow))*512 + h*64;
  float areg[16];
  #pragma unroll
  for(int ks=0;ks<2;ks++){
    float4 u0 = *(const float4*)(qr + ks*32 + g*8);
    float4 u1 = *(const float4*)(qr + ks*32 + g*8 + 4);
    areg[ks*8+0]=u0.x; areg[ks*8+1]=u0.y; areg[ks*8+2]=u0.z; areg[ks*8+3]=u0.w;
    areg[ks*8+4]=u1.x; areg[ks*8+5]=u1.y; areg[ks*8+6]=u1.z; areg[ks*8+7]=u1.w;
  }
  float qsq = 0.f;
  #pragma unroll
  for(int e=0;e<16;e++) qsq = fmaf(areg[e], areg[e], qsq);
  qsq += __shfl_xor(qsq, 16);
  qsq += __shfl_xor(qsq, 32);
  qsq *= 0.5f;
  short8 ah[2], al[2];
  #pragma unroll
  for(int ks=0;ks<2;ks++){
    #pragma unroll
    for(int j=0;j<8;j++){
      float x = areg[ks*8+j];
      u16 hb = f2b(x);
      ah[ks][j] = (short)hb;
      al[ks][j] = (short)f2b(x - b2f(hb));
    }
  }
  __syncthreads();   // kvtA, k1s ready

  // ---- A1: logq MFMA
  f32x4 acc[8];
  #pragma unroll
  for(int mt=0;mt<8;mt++) acc[mt] = zero4;
  #pragma unroll
  for(int ks=0;ks<2;ks++){
    #pragma unroll
    for(int mt=0;mt<8;mt++){
      const float* pb = projc + (mt*16 + r16)*64 + ks*32 + g*8;
      float4 u0 = *(const float4*)pb;
      float4 u1 = *(const float4*)(pb + 4);
      float x[8] = {u0.x,u0.y,u0.z,u0.w,u1.x,u1.y,u1.z,u1.w};
      short8 pph, ppl;
      #pragma unroll
      for(int j=0;j<8;j++){
        u16 hb = f2b(x[j]);
        pph[j] = (short)hb;
        ppl[j] = (short)f2b(x[j] - b2f(hb));
      }
      acc[mt] = __builtin_amdgcn_mfma_f32_16x16x32_bf16(ah[ks], pph, acc[mt], 0, 0, 0);
      acc[mt] = __builtin_amdgcn_mfma_f32_16x16x32_bf16(ah[ks], ppl, acc[mt], 0, 0, 0);
      acc[mt] = __builtin_amdgcn_mfma_f32_16x16x32_bf16(al[ks], pph, acc[mt], 0, 0, 0);
    }
  }
  float qsr[4];
  #pragma unroll
  for(int r=0;r<4;r++) qsr[r] = __shfl(qsq, 4*g + r);
  float amax[4];
  #pragma unroll
  for(int r=0;r<4;r++){
    float m = -3e38f;
    #pragma unroll
    for(int mt=0;mt<8;mt++) m = fmaxf(m, acc[mt][r]);
    m = fmaxf(m, __shfl_xor(m, 1));
    m = fmaxf(m, __shfl_xor(m, 2));
    m = fmaxf(m, __shfl_xor(m, 4));
    m = fmaxf(m, __shfl_xor(m, 8));
    amax[r] = m;
  }
  float lrp[4] = {0.f,0.f,0.f,0.f};
  #pragma unroll
  for(int mt=0;mt<8;mt++){
    const float k1v = k1s[mt*16 + r16];
    #pragma unroll
    for(int r=0;r<4;r++){
      float phv = __expf(acc[mt][r] - amax[r]);
      phiqsA[(wave*16 + 4*g + r)*136 + mt*16 + r16] = f2b(phv);
      lrp[r] = fmaf(phv, k1v, lrp[r]);
    }
  }
  #pragma unroll
  for(int r=0;r<4;r++){
    lrp[r] += __shfl_xor(lrp[r], 1);
    lrp[r] += __shfl_xor(lrp[r], 2);
    lrp[r] += __shfl_xor(lrp[r], 4);
    lrp[r] += __shfl_xor(lrp[r], 8);
  }
  // per-row scalars, uniform across the 16-lane group — keep in registers
  float plsr[4], lr1r[4];
  #pragma unroll
  for(int r=0;r<4;r++){
    plsr[r] = amax[r] - qsr[r] + stab - LOGM;
    lr1r[r] = lrp[r];
  }
  __syncthreads();   // phiqsA complete

  // ---- A2: phi_q A-fragments + lr_v MFMA (f32, kept in regs)
  short8 pa[4];
  #pragma unroll
  for(int ks=0;ks<4;ks++)
    pa[ks] = *(const short8*)(phiqsA + (wave*16 + r16)*136 + ks*32 + g*8);
  f32x4 lacc[4];
  #pragma unroll
  for(int dt=0;dt<4;dt++) lacc[dt] = zero4;
  #pragma unroll
  for(int ks=0;ks<4;ks++){
    #pragma unroll
    for(int dt=0;dt<4;dt++){
      short8 bfr = *(const short8*)(kvtA + (dt*16 + r16)*136 + ks*32 + g*8);
      lacc[dt] = __builtin_amdgcn_mfma_f32_16x16x32_bf16(pa[ks], bfr, lacc[dt], 0, 0, 0);
    }
  }
  __syncthreads();   // all phase-A LDS reads done; buf may be overwritten

  // ---- B0: stage k window (hi/lo) + phi_k window into LDS; v into regs
  const u16* phikg = ((const u16*)(ws + WS_PHIK)) + (size_t)combo*1056*128;
  float4 vreg[6];
  #pragma unroll
  for(int i=0;i<6;i++){
    int flat = tid + 256*i;
    int j = flat >> 4, e4 = (flat & 15)*4;
    int s = s_base + j;
    float4 u = {0.f,0.f,0.f,0.f};
    float4 w4 = {0.f,0.f,0.f,0.f};
    if(s >= 0){
      u  = *(const float4*)(key + (((size_t)b*4096 + s)*8 + h)*64 + e4);
      w4 = *(const float4*)(val + (((size_t)b*4096 + s)*8 + h)*64 + e4);
    }
    vreg[i] = w4;
    ushort4 hh, ll;
    hh.x = f2b(u.x); ll.x = f2b(u.x - b2f(hh.x));
    hh.y = f2b(u.y); ll.y = f2b(u.y - b2f(hh.y));
    hh.z = f2b(u.z); ll.z = f2b(u.z - b2f(hh.z));
    hh.w = f2b(u.w); ll.w = f2b(u.w - b2f(hh.w));
    *(ushort4*)(khs + j*72 + e4) = hh;
    *(ushort4*)(kls + j*72 + e4) = ll;
  }
  #pragma unroll
  for(int i=0;i<12;i++){
    int flat = tid + 256*i;
    int j = flat >> 5, c4 = (flat & 31)*4;
    int s = s_base + j;
    ushort4 p = {0,0,0,0};
    if(s >= 0) p = *(const ushort4*)(phikg + (size_t)s*128 + c4);
    *(ushort4*)(phik + j*136 + c4) = p;
  }
  __syncthreads();

  // ---- B1: S (scores) and D (dots_p) over the full 16x96 stripe
  f32x4 sacc[6], dacc[6];
  #pragma unroll
  for(int j=0;j<6;j++){ sacc[j] = zero4; dacc[j] = zero4; }
  #pragma unroll
  for(int j=0;j<6;j++){
    #pragma unroll
    for(int ks=0;ks<2;ks++){
      short8 kbh = *(const short8*)(khs + (j*16 + r16)*72 + ks*32 + g*8);
      short8 kbl = *(const short8*)(kls + (j*16 + r16)*72 + ks*32 + g*8);
      sacc[j] = __builtin_amdgcn_mfma_f32_16x16x32_bf16(ah[ks], kbh, sacc[j], 0, 0, 0);
      sacc[j] = __builtin_amdgcn_mfma_f32_16x16x32_bf16(al[ks], kbh, sacc[j], 0, 0, 0);
      sacc[j] = __builtin_amdgcn_mfma_f32_16x16x32_bf16(ah[ks], kbl, sacc[j], 0, 0, 0);
    }
    #pragma unroll
    for(int ks=0;ks<4;ks++){
      short8 pb = *(const short8*)(phik + (j*16 + r16)*136 + ks*32 + g*8);
      dacc[j] = __builtin_amdgcn_mfma_f32_16x16x32_bf16(pa[ks], pb, dacc[j], 0, 0, 0);
    }
  }
  __syncthreads();   // all B1 LDS reads done; region reused below

  // ---- B2: v -> LDS (transposed, hi/lo); in-register softmax/normalizer; cj -> LDS
  #pragma unroll
  for(int i=0;i<6;i++){
    int flat = tid + 256*i;
    int j = flat >> 4, e4 = (flat & 15)*4;
    float4 u = vreg[i];
    u16 h0 = f2b(u.x), h1 = f2b(u.y), h2 = f2b(u.z), h3 = f2b(u.w);
    vt[(e4+0)*104 + j] = h0; vtl[(e4+0)*104 + j] = f2b(u.x - b2f(h0));
    vt[(e4+1)*104 + j] = h1; vtl[(e4+1)*104 + j] = f2b(u.y - b2f(h1));
    vt[(e4+2)*104 + j] = h2; vtl[(e4+2)*104 + j] = f2b(u.z - b2f(h2));
    vt[(e4+3)*104 + j] = h3; vtl[(e4+3)*104 + j] = f2b(u.w - b2f(h3));
  }
  const int rowb = wave*16 + 4*g;
  float m1r[4] = {-1e30f,-1e30f,-1e30f,-1e30f};
  #pragma unroll
  for(int j=0;j<6;j++){
    #pragma unroll
    for(int r=0;r<4;r++){
      int rel = 16*j + r16 - 16 - (rowb + r);
      bool ok = (rel >= -16) && (rel < 16) && (s_base + 16*j + r16 >= 0);
      if(ok) m1r[r] = fmaxf(m1r[r], sacc[j][r]);
    }
  }
  #pragma unroll
  for(int r=0;r<4;r++){
    m1r[r] = fmaxf(m1r[r], __shfl_xor(m1r[r], 1));
    m1r[r] = fmaxf(m1r[r], __shfl_xor(m1r[r], 2));
    m1r[r] = fmaxf(m1r[r], __shfl_xor(m1r[r], 4));
    m1r[r] = fmaxf(m1r[r], __shfl_xor(m1r[r], 8));
  }
  float ser[4] = {0.f,0.f,0.f,0.f}, wpr[4] = {0.f,0.f,0.f,0.f};
  #pragma unroll
  for(int j=0;j<6;j++){
    #pragma unroll
    for(int r=0;r<4;r++){
      int rel = 16*j + r16 - 16 - (rowb + r);
      bool ok = (rel >= -16) && (rel < 16) && (s_base + 16*j + r16 >= 0);
      if(ok){
        ser[r] += __expf(sacc[j][r] - m1r[r]);
        wpr[r] += dacc[j][r];
      }
    }
  }
  #pragma unroll
  for(int r=0;r<4;r++){
    ser[r] += __shfl_xor(ser[r], 1); ser[r] += __shfl_xor(ser[r], 2);
    ser[r] += __shfl_xor(ser[r], 4); ser[r] += __shfl_xor(ser[r], 8);
    wpr[r] += __shfl_xor(wpr[r], 1); wpr[r] += __shfl_xor(wpr[r], 2);
    wpr[r] += __shfl_xor(wpr[r], 4); wpr[r] += __shfl_xor(wpr[r], 8);
  }
  float lnr[4], scr[4];
  #pragma unroll
  for(int r=0;r<4;r++){
    float qk_lse = m1r[r] + __logf(ser[r]);
    float lrem = fmaxf(lr1r[r] - wpr[r], 1e-37f);
    float bb = __logf(lrem) + plsr[r];
    float ln = fmaxf(qk_lse, bb) + log1pf(__expf(-fabsf(qk_lse - bb)));
    lnr[r] = ln;
    scr[r] = __expf(plsr[r] - ln);
  }
  #pragma unroll
  for(int j=0;j<6;j++){
    #pragma unroll
    for(int r=0;r<4;r++){
      int rel = 16*j + r16 - 16 - (rowb + r);
      bool ok = (rel >= -16) && (rel < 16) && (s_base + 16*j + r16 >= 0);
      float cj = ok ? (__expf(sacc[j][r] - lnr[r]) - scr[r]*dacc[j][r]) : 0.f;
      u16 hb = f2b(cj);
      cjh[(rowb + r)*136 + 16*j + r16] = hb;
      cjl[(rowb + r)*136 + 16*j + r16] = f2b(cj - b2f(hb));
    }
  }
  __syncthreads();

  // ---- B3: out = cj . v_win (hi/lo split) + scale*lr_v (lacc, f32)
  f32x4 oacc[4];
  #pragma unroll
  for(int dt=0;dt<4;dt++) oacc[dt] = zero4;
  #pragma unroll
  for(int ks=0;ks<3;ks++){
    short8 ch = *(const short8*)(cjh + (wave*16 + r16)*136 + ks*32 + g*8);
    short8 cl = *(const short8*)(cjl + (wave*16 + r16)*136 + ks*32 + g*8);
    #pragma unroll
    for(int dt=0;dt<4;dt++){
      short8 vbh = *(const short8*)(vt  + (dt*16 + r16)*104 + ks*32 + g*8);
      short8 vbl = *(const short8*)(vtl + (dt*16 + r16)*104 + ks*32 + g*8);
      oacc[dt] = __builtin_amdgcn_mfma_f32_16x16x32_bf16(ch, vbh, oacc[dt], 0, 0, 0);
      oacc[dt] = __builtin_amdgcn_mfma_f32_16x16x32_bf16(cl, vbh, oacc[dt], 0, 0, 0);
      oacc[dt] = __builtin_amdgcn_mfma_f32_16x16x32_bf16(ch, vbl, oacc[dt], 0, 0, 0);
    }
  }
  #pragma unroll
  for(int r=0;r<4;r++){
    int row = rowb + r;                      // query within 64
    float* ob = out + ((((size_t)b*8 + h)*4096) + (size_t)c*1024 + qt*64 + row)*64;
    #pragma unroll
    for(int dt=0;dt<4;dt++)
      ob[dt*16 + r16] = oacc[dt][r] + scr[r]*lacc[dt][r];
  }
}

extern "C" void kernel_launch(void* const* d_in, const int* in_sizes, int n_in,
                              void* d_out, int out_size, void* d_ws, size_t ws_size,
                              hipStream_t stream){
  (void)in_sizes; (void)n_in; (void)out_size; (void)ws_size;
  const float* q = (const float*)d_in[0];
  const float* k = (const float*)d_in[1];
  const float* v = (const float*)d_in[2];
  const float* p = (const float*)d_in[3];
  float* out = (float*)d_out;
  float* ws = (float*)d_ws;
  hipMemsetAsync(ws + WS_K1, 0, (size_t)(16384 + 1048576)*sizeof(float), stream);
  k_stab<<<dim3(4),      128, 0, stream>>>(p, ws);
  k_phi <<<dim3(4,128),  256, 0, stream>>>(k, v, p, ws);
  k_qm  <<<dim3(16,128), 256, 0, stream>>>(q, k, v, p, ws, out);
}

// Round 11
// 315.942 us; speedup vs baseline: 1.2506x; 1.0257x over previous
//
#include <hip/hip_runtime.h>

typedef unsigned short u16;
typedef unsigned int   u32;
typedef __attribute__((ext_vector_type(8))) short short8;
typedef __attribute__((ext_vector_type(4))) float f32x4;

#define LOGM 4.852030263919617f

// workspace layout (float offsets)
constexpr int WS_PMAX = 0;         // 128 floats (per-combo stabilizer bound, by k_stab)
constexpr int WS_K1   = 2048;      // 128*128 floats (k1sum, atomic-accumulated)
constexpr int WS_KV   = 18432;     // 128*128*64 floats (kv [m][d], atomic-accumulated)
constexpr int WS_PHIK = 1067008;   // u16: 128 combos * 1056 * 128 (phi_k bf16, [s][m])

__device__ __forceinline__ float b2f(u16 u){ union { u32 i; float f; } x; x.i = ((u32)u) << 16; return x.f; }
__device__ __forceinline__ u16 f2b(float f){ union { float f; u32 i; } x; x.f = f; return (u16)((x.i + 0x7fffu + ((x.i >> 16) & 1u)) >> 16); }

// ================= k_stab: per-c proj stabilizer (4 values), once =================
__global__ __launch_bounds__(128) void k_stab(const float* __restrict__ proj,
                                              float* __restrict__ ws){
  __shared__ float red[2];
  const int c = blockIdx.x, tid = threadIdx.x;
  const int wave = tid >> 6, l = tid & 63;
  const float4* pr = (const float4*)(proj + c*8192 + tid*64);
  float pn = 0.f;
  #pragma unroll
  for(int i=0;i<16;i++){ float4 u = pr[i]; pn = fmaf(u.x,u.x,fmaf(u.y,u.y,fmaf(u.z,u.z,fmaf(u.w,u.w,pn)))); }
  #pragma unroll
  for(int o=1;o<64;o<<=1) pn = fmaxf(pn, __shfl_xor(pn, o));
  if(l == 0) red[wave] = pn;
  __syncthreads();
  const float stab = 0.5f * fmaxf(red[0], red[1]);
  if(tid < 32) ws[WS_PMAX + c*32 + tid] = stab;   // all combos with this c
}

// ================= k_phi: logk MFMA -> phi_k -> ws; kv & k1 atomics =================
// (r9 verified: interleaved tile map + hoisted stab; 122 us)
__global__ __launch_bounds__(256, 2) void k_phi(const float* __restrict__ key,
                                                const float* __restrict__ val,
                                                const float* __restrict__ proj,
                                                float* __restrict__ ws){
  __shared__ __align__(16) u16 phit[128*72];   // [m][key64] bf16, stride 72
  __shared__ __align__(16) u16 vt[64*72];      // [d][key64] bf16, stride 72, col-swizzled
  const int tid = threadIdx.x;
  const int wave = tid >> 6, l = tid & 63;
  const int g = l >> 4, r16 = l & 15;
  const int kq = blockIdx.x, combo = blockIdx.y;
  const int c = combo >> 5, b = (combo >> 3) & 3, h = combo & 7;
  const float* projc = proj + c*8192;
  const float stab = ws[WS_PMAX + combo];

  short8 ph[8][2], pl[8][2];
  #pragma unroll
  for(int mt=0;mt<8;mt++){
    #pragma unroll
    for(int ks=0;ks<2;ks++){
      const float* pb = projc + (mt*16 + r16)*64 + ks*32 + g*8;
      float4 u0 = *(const float4*)pb;
      float4 u1 = *(const float4*)(pb + 4);
      float x[8] = {u0.x,u0.y,u0.z,u0.w,u1.x,u1.y,u1.z,u1.w};
      #pragma unroll
      for(int j=0;j<8;j++){
        u16 hb = f2b(x[j]);
        ph[mt][ks][j] = (short)hb;
        pl[mt][ks][j] = (short)f2b(x[j] - b2f(hb));
      }
    }
  }

  const f32x4 zero4 = {0.f,0.f,0.f,0.f};
  f32x4 kvacc[2][4];
  #pragma unroll
  for(int i=0;i<2;i++)
    #pragma unroll
    for(int j=0;j<4;j++) kvacc[i][j] = zero4;
  float k1p0 = 0.f, k1p1 = 0.f;
  u16* phikg = ((u16*)(ws + WS_PHIK)) + (size_t)combo*1056*128;

  for(int t0=0;t0<16;t0++){
    const int s_tile = (kq + 4*t0)*64;      // interleaved tile map
    const bool dtile = (s_tile < 1056);
    const int sA = s_tile + wave*16 + r16;
    const float* krow = key + (size_t)(b*4096 + sA)*512 + h*64;
    float areg[16];
    #pragma unroll
    for(int ks=0;ks<2;ks++){
      float4 u0 = *(const float4*)(krow + ks*32 + g*8);
      float4 u1 = *(const float4*)(krow + ks*32 + g*8 + 4);
      areg[ks*8+0]=u0.x; areg[ks*8+1]=u0.y; areg[ks*8+2]=u0.z; areg[ks*8+3]=u0.w;
      areg[ks*8+4]=u1.x; areg[ks*8+5]=u1.y; areg[ks*8+6]=u1.z; areg[ks*8+7]=u1.w;
    }
    float4 vreg[4];
    #pragma unroll
    for(int i=0;i<4;i++){
      int flat = tid + 256*i;
      int sv = flat >> 4, d4 = (flat & 15)*4;
      vreg[i] = *(const float4*)(val + (size_t)(b*4096 + s_tile + sv)*512 + h*64 + d4);
    }
    float ksq = 0.f;
    #pragma unroll
    for(int e=0;e<16;e++) ksq = fmaf(areg[e], areg[e], ksq);
    ksq += __shfl_xor(ksq, 16);
    ksq += __shfl_xor(ksq, 32);
    ksq *= 0.5f;
    short8 ah[2], al[2];
    #pragma unroll
    for(int ks=0;ks<2;ks++){
      #pragma unroll
      for(int j=0;j<8;j++){
        float x = areg[ks*8+j];
        u16 hb = f2b(x);
        ah[ks][j] = (short)hb;
        al[ks][j] = (short)f2b(x - b2f(hb));
      }
    }
    f32x4 acc[8];
    #pragma unroll
    for(int mt=0;mt<8;mt++) acc[mt] = zero4;
    #pragma unroll
    for(int ks=0;ks<2;ks++){
      #pragma unroll
      for(int mt=0;mt<8;mt++){
        acc[mt] = __builtin_amdgcn_mfma_f32_16x16x32_bf16(ah[ks], ph[mt][ks], acc[mt], 0, 0, 0);
        acc[mt] = __builtin_amdgcn_mfma_f32_16x16x32_bf16(ah[ks], pl[mt][ks], acc[mt], 0, 0, 0);
        acc[mt] = __builtin_amdgcn_mfma_f32_16x16x32_bf16(al[ks], ph[mt][ks], acc[mt], 0, 0, 0);
      }
    }
    const float kc0 = __shfl(ksq, 4*g + 0);
    const float kc1 = __shfl(ksq, 4*g + 1);
    const float kc2 = __shfl(ksq, 4*g + 2);
    const float kc3 = __shfl(ksq, 4*g + 3);
    const int gs = s_tile + wave*16 + r16;
    #pragma unroll
    for(int mt=0;mt<8;mt++){
      ushort4 pw;
      pw.x = f2b(__expf(acc[mt][0] - kc0 - stab));
      pw.y = f2b(__expf(acc[mt][1] - kc1 - stab));
      pw.z = f2b(__expf(acc[mt][2] - kc2 - stab));
      pw.w = f2b(__expf(acc[mt][3] - kc3 - stab));
      *(ushort4*)(phit + (mt*16 + r16)*72 + wave*16 + 4*g) = pw;
      if(dtile && gs < 1056)
        *(ushort4*)(phikg + (size_t)gs*128 + mt*16 + 4*g) = pw;
    }
    #pragma unroll
    for(int i=0;i<4;i++){
      int flat = tid + 256*i;
      int sv = flat >> 4, d4 = (flat & 15)*4;
      float x[4] = {vreg[i].x, vreg[i].y, vreg[i].z, vreg[i].w};
      #pragma unroll
      for(int j=0;j<4;j++){
        int d = d4 + j;
        vt[d*72 + (sv ^ (8*((d>>2)&7)))] = f2b(x[j]);
      }
    }
    __syncthreads();
    #pragma unroll
    for(int ks=0;ks<2;ks++){
      short8 af0 = *(const short8*)(phit + ((2*wave+0)*16 + r16)*72 + ks*32 + g*8);
      short8 af1 = *(const short8*)(phit + ((2*wave+1)*16 + r16)*72 + ks*32 + g*8);
      short8 bf[4];
      #pragma unroll
      for(int dt=0;dt<4;dt++){
        int d = dt*16 + r16;
        int col = (ks*32 + g*8) ^ (8*((d>>2)&7));
        bf[dt] = *(const short8*)(vt + d*72 + col);
      }
      #pragma unroll
      for(int dt=0;dt<4;dt++){
        kvacc[0][dt] = __builtin_amdgcn_mfma_f32_16x16x32_bf16(af0, bf[dt], kvacc[0][dt], 0, 0, 0);
        kvacc[1][dt] = __builtin_amdgcn_mfma_f32_16x16x32_bf16(af1, bf[dt], kvacc[1][dt], 0, 0, 0);
      }
      #pragma unroll
      for(int j=0;j<8;j++){ k1p0 += b2f((u16)af0[j]); k1p1 += b2f((u16)af1[j]); }
    }
    __syncthreads();
  }
  k1p0 += __shfl_xor(k1p0, 16); k1p0 += __shfl_xor(k1p0, 32);
  k1p1 += __shfl_xor(k1p1, 16); k1p1 += __shfl_xor(k1p1, 32);
  if(l < 16){
    atomicAdd(ws + WS_K1 + combo*128 + (2*wave+0)*16 + l, k1p0);
    atomicAdd(ws + WS_K1 + combo*128 + (2*wave+1)*16 + l, k1p1);
  }
  #pragma unroll
  for(int mi=0;mi<2;mi++){
    #pragma unroll
    for(int dt=0;dt<4;dt++){
      #pragma unroll
      for(int rr=0;rr<4;rr++){
        int m = (2*wave+mi)*16 + 4*g + rr;
        int d = dt*16 + r16;
        atomicAdd(ws + WS_KV + (size_t)combo*8192 + m*64 + d, kvacc[mi][dt][rr]);
      }
    }
  }
}

// ================= k_qm: fused k_q + k_main =================
// r11: (1) T14 hoist — ALL phase-B global loads (k window, v window, phi_k window)
// issued at kernel top into regs (~+60 VGPR), consumed after the A2 barrier; their
// HBM latency hides under phase A's ~100 MFMAs. (2) XOR write-swizzles on the
// transpose stores: kvtA (16->4-way), vt/vtl (16->8-way), cj (4->2-way).
__global__ __launch_bounds__(256, 2) void k_qm(const float* __restrict__ qry,
                                               const float* __restrict__ key,
                                               const float* __restrict__ val,
                                               const float* __restrict__ proj,
                                               float* __restrict__ ws,
                                               float* __restrict__ out){
  __shared__ __align__(16) u16 buf[30720];   // 61440 B
  // phase A layout
  u16* kvtA   = buf;            // [d][m] stride 136, col-swizzled
  u16* phiqsA = buf + 8704;     // [q][m] stride 136
  float* k1s  = (float*)(buf + 17408);   // 128 floats
  // phase B layout (overlays; all phase-A reads complete before reuse)
  u16* khs  = buf;              // [96][72]
  u16* kls  = buf + 6912;
  u16* phik = buf + 13824;      // [96][136]
  u16* cjh  = buf;              // [64][136], col-swizzled
  u16* cjl  = buf + 8704;
  u16* vt   = buf + 17408;      // [64][104], col-swizzled
  u16* vtl  = buf + 24064;

  const int tid = threadIdx.x;
  const int wave = tid >> 6, l = tid & 63;
  const int g = l >> 4, r16 = l & 15;
  const int qt = blockIdx.x, combo = blockIdx.y;
  const int c = combo >> 5, b = (combo >> 3) & 3, h = combo & 7;
  const int s_base = qt*64 - 16;
  const float* projc = proj + c*8192;
  const float stab = ws[WS_PMAX + combo];
  const f32x4 zero4 = {0.f,0.f,0.f,0.f};

  // ---- prefetch ALL phase-B global inputs (consumed after A2) — T14
  const u16* phikg = ((const u16*)(ws + WS_PHIK)) + (size_t)combo*1056*128;
  float4 kreg[6], vreg[6];
  ushort4 preg[12];
  #pragma unroll
  for(int i=0;i<6;i++){
    int flat = tid + 256*i;
    int j = flat >> 4, e4 = (flat & 15)*4;
    int s = s_base + j;
    float4 u = {0.f,0.f,0.f,0.f};
    float4 w4 = {0.f,0.f,0.f,0.f};
    if(s >= 0){
      u  = *(const float4*)(key + (((size_t)b*4096 + s)*8 + h)*64 + e4);
      w4 = *(const float4*)(val + (((size_t)b*4096 + s)*8 + h)*64 + e4);
    }
    kreg[i] = u; vreg[i] = w4;
  }
  #pragma unroll
  for(int i=0;i<12;i++){
    int flat = tid + 256*i;
    int j = flat >> 5, c4 = (flat & 31)*4;
    int s = s_base + j;
    ushort4 p = {0,0,0,0};
    if(s >= 0) p = *(const ushort4*)(phikg + (size_t)s*128 + c4);
    preg[i] = p;
  }

  // ---- A0: k1s + kv -> LDS (transposed bf16, col-swizzled)
  if(tid < 128) k1s[tid] = ws[WS_K1 + combo*128 + tid];
  const float* kvg = ws + WS_KV + (size_t)combo*8192;
  #pragma unroll
  for(int i=0;i<8;i++){
    int flat = tid + 256*i;
    int m = flat >> 4, d4 = (flat & 15)*4;
    int col = m ^ (8*((flat & 15) & 7));   // swz by (d>>2)&7 = (flat&15)&7
    float4 u = *(const float4*)(kvg + m*64 + d4);
    kvtA[(d4+0)*136 + col] = f2b(u.x);
    kvtA[(d4+1)*136 + col] = f2b(u.y);
    kvtA[(d4+2)*136 + col] = f2b(u.z);
    kvtA[(d4+3)*136 + col] = f2b(u.w);
  }
  // q fragments (hi/lo) — used by BOTH logq (phase A) and scores (phase B)
  const int qrow = qt*64 + wave*16 + r16;
  const float* qr = qry + (size_t)(b*4096 + (c*1024 + qrow))*512 + h*64;
  float areg[16];
  #pragma unroll
  for(int ks=0;ks<2;ks++){
    float4 u0 = *(const float4*)(qr + ks*32 + g*8);
    float4 u1 = *(const float4*)(qr + ks*32 + g*8 + 4);
    areg[ks*8+0]=u0.x; areg[ks*8+1]=u0.y; areg[ks*8+2]=u0.z; areg[ks*8+3]=u0.w;
    areg[ks*8+4]=u1.x; areg[ks*8+5]=u1.y; areg[ks*8+6]=u1.z; areg[ks*8+7]=u1.w;
  }
  float qsq = 0.f;
  #pragma unroll
  for(int e=0;e<16;e++) qsq = fmaf(areg[e], areg[e], qsq);
  qsq += __shfl_xor(qsq, 16);
  qsq += __shfl_xor(qsq, 32);
  qsq *= 0.5f;
  short8 ah[2], al[2];
  #pragma unroll
  for(int ks=0;ks<2;ks++){
    #pragma unroll
    for(int j=0;j<8;j++){
      float x = areg[ks*8+j];
      u16 hb = f2b(x);
      ah[ks][j] = (short)hb;
      al[ks][j] = (short)f2b(x - b2f(hb));
    }
  }
  __syncthreads();   // kvtA, k1s ready

  // ---- A1: logq MFMA
  f32x4 acc[8];
  #pragma unroll
  for(int mt=0;mt<8;mt++) acc[mt] = zero4;
  #pragma unroll
  for(int ks=0;ks<2;ks++){
    #pragma unroll
    for(int mt=0;mt<8;mt++){
      const float* pb = projc + (mt*16 + r16)*64 + ks*32 + g*8;
      float4 u0 = *(const float4*)pb;
      float4 u1 = *(const float4*)(pb + 4);
      float x[8] = {u0.x,u0.y,u0.z,u0.w,u1.x,u1.y,u1.z,u1.w};
      short8 pph, ppl;
      #pragma unroll
      for(int j=0;j<8;j++){
        u16 hb = f2b(x[j]);
        pph[j] = (short)hb;
        ppl[j] = (short)f2b(x[j] - b2f(hb));
      }
      acc[mt] = __builtin_amdgcn_mfma_f32_16x16x32_bf16(ah[ks], pph, acc[mt], 0, 0, 0);
      acc[mt] = __builtin_amdgcn_mfma_f32_16x16x32_bf16(ah[ks], ppl, acc[mt], 0, 0, 0);
      acc[mt] = __builtin_amdgcn_mfma_f32_16x16x32_bf16(al[ks], pph, acc[mt], 0, 0, 0);
    }
  }
  float qsr[4];
  #pragma unroll
  for(int r=0;r<4;r++) qsr[r] = __shfl(qsq, 4*g + r);
  float amax[4];
  #pragma unroll
  for(int r=0;r<4;r++){
    float m = -3e38f;
    #pragma unroll
    for(int mt=0;mt<8;mt++) m = fmaxf(m, acc[mt][r]);
    m = fmaxf(m, __shfl_xor(m, 1));
    m = fmaxf(m, __shfl_xor(m, 2));
    m = fmaxf(m, __shfl_xor(m, 4));
    m = fmaxf(m, __shfl_xor(m, 8));
    amax[r] = m;
  }
  float lrp[4] = {0.f,0.f,0.f,0.f};
  #pragma unroll
  for(int mt=0;mt<8;mt++){
    const float k1v = k1s[mt*16 + r16];
    #pragma unroll
    for(int r=0;r<4;r++){
      float phv = __expf(acc[mt][r] - amax[r]);
      phiqsA[(wave*16 + 4*g + r)*136 + mt*16 + r16] = f2b(phv);
      lrp[r] = fmaf(phv, k1v, lrp[r]);
    }
  }
  #pragma unroll
  for(int r=0;r<4;r++){
    lrp[r] += __shfl_xor(lrp[r], 1);
    lrp[r] += __shfl_xor(lrp[r], 2);
    lrp[r] += __shfl_xor(lrp[r], 4);
    lrp[r] += __shfl_xor(lrp[r], 8);
  }
  float plsr[4], lr1r[4];
  #pragma unroll
  for(int r=0;r<4;r++){
    plsr[r] = amax[r] - qsr[r] + stab - LOGM;
    lr1r[r] = lrp[r];
  }
  __syncthreads();   // phiqsA complete

  // ---- A2: phi_q A-fragments + lr_v MFMA (f32, kept in regs)
  short8 pa[4];
  #pragma unroll
  for(int ks=0;ks<4;ks++)
    pa[ks] = *(const short8*)(phiqsA + (wave*16 + r16)*136 + ks*32 + g*8);
  f32x4 lacc[4];
  #pragma unroll
  for(int dt=0;dt<4;dt++) lacc[dt] = zero4;
  #pragma unroll
  for(int ks=0;ks<4;ks++){
    #pragma unroll
    for(int dt=0;dt<4;dt++){
      int drow = dt*16 + r16;
      int colb = (ks*32 + g*8) ^ (8*((drow>>2)&7));
      short8 bfr = *(const short8*)(kvtA + drow*136 + colb);
      lacc[dt] = __builtin_amdgcn_mfma_f32_16x16x32_bf16(pa[ks], bfr, lacc[dt], 0, 0, 0);
    }
  }
  __syncthreads();   // all phase-A LDS reads done; buf may be overwritten

  // ---- B0: write prefetched k window (hi/lo) + phi_k window to LDS
  #pragma unroll
  for(int i=0;i<6;i++){
    int flat = tid + 256*i;
    int j = flat >> 4, e4 = (flat & 15)*4;
    float4 u = kreg[i];
    ushort4 hh, ll;
    hh.x = f2b(u.x); ll.x = f2b(u.x - b2f(hh.x));
    hh.y = f2b(u.y); ll.y = f2b(u.y - b2f(hh.y));
    hh.z = f2b(u.z); ll.z = f2b(u.z - b2f(hh.z));
    hh.w = f2b(u.w); ll.w = f2b(u.w - b2f(hh.w));
    *(ushort4*)(khs + j*72 + e4) = hh;
    *(ushort4*)(kls + j*72 + e4) = ll;
  }
  #pragma unroll
  for(int i=0;i<12;i++){
    int flat = tid + 256*i;
    int j = flat >> 5, c4 = (flat & 31)*4;
    *(ushort4*)(phik + j*136 + c4) = preg[i];
  }
  __syncthreads();

  // ---- B1: S (scores) and D (dots_p) over the full 16x96 stripe
  f32x4 sacc[6], dacc[6];
  #pragma unroll
  for(int j=0;j<6;j++){ sacc[j] = zero4; dacc[j] = zero4; }
  #pragma unroll
  for(int j=0;j<6;j++){
    #pragma unroll
    for(int ks=0;ks<2;ks++){
      short8 kbh = *(const short8*)(khs + (j*16 + r16)*72 + ks*32 + g*8);
      short8 kbl = *(const short8*)(kls + (j*16 + r16)*72 + ks*32 + g*8);
      sacc[j] = __builtin_amdgcn_mfma_f32_16x16x32_bf16(ah[ks], kbh, sacc[j], 0, 0, 0);
      sacc[j] = __builtin_amdgcn_mfma_f32_16x16x32_bf16(al[ks], kbh, sacc[j], 0, 0, 0);
      sacc[j] = __builtin_amdgcn_mfma_f32_16x16x32_bf16(ah[ks], kbl, sacc[j], 0, 0, 0);
    }
    #pragma unroll
    for(int ks=0;ks<4;ks++){
      short8 pb = *(const short8*)(phik + (j*16 + r16)*136 + ks*32 + g*8);
      dacc[j] = __builtin_amdgcn_mfma_f32_16x16x32_bf16(pa[ks], pb, dacc[j], 0, 0, 0);
    }
  }
  __syncthreads();   // all B1 LDS reads done; region reused below

  // ---- B2: v -> LDS (transposed, hi/lo, col-swizzled); softmax; cj -> LDS (swizzled)
  #pragma unroll
  for(int i=0;i<6;i++){
    int flat = tid + 256*i;
    int j = flat >> 4, e4 = (flat & 15)*4;
    int e = flat & 15;
    int col = j ^ (8*(e & 3));             // swz by (row>>2)&3 = e&3; col <= 95 safe
    float4 u = vreg[i];
    u16 h0 = f2b(u.x), h1 = f2b(u.y), h2 = f2b(u.z), h3 = f2b(u.w);
    vt[(e4+0)*104 + col] = h0; vtl[(e4+0)*104 + col] = f2b(u.x - b2f(h0));
    vt[(e4+1)*104 + col] = h1; vtl[(e4+1)*104 + col] = f2b(u.y - b2f(h1));
    vt[(e4+2)*104 + col] = h2; vtl[(e4+2)*104 + col] = f2b(u.z - b2f(h2));
    vt[(e4+3)*104 + col] = h3; vtl[(e4+3)*104 + col] = f2b(u.w - b2f(h3));
  }
  const int rowb = wave*16 + 4*g;
  float m1r[4] = {-1e30f,-1e30f,-1e30f,-1e30f};
  #pragma unroll
  for(int j=0;j<6;j++){
    #pragma unroll
    for(int r=0;r<4;r++){
      int rel = 16*j + r16 - 16 - (rowb + r);
      bool ok = (rel >= -16) && (rel < 16) && (s_base + 16*j + r16 >= 0);
      if(ok) m1r[r] = fmaxf(m1r[r], sacc[j][r]);
    }
  }
  #pragma unroll
  for(int r=0;r<4;r++){
    m1r[r] = fmaxf(m1r[r], __shfl_xor(m1r[r], 1));
    m1r[r] = fmaxf(m1r[r], __shfl_xor(m1r[r], 2));
    m1r[r] = fmaxf(m1r[r], __shfl_xor(m1r[r], 4));
    m1r[r] = fmaxf(m1r[r], __shfl_xor(m1r[r], 8));
  }
  float ser[4] = {0.f,0.f,0.f,0.f}, wpr[4] = {0.f,0.f,0.f,0.f};
  #pragma unroll
  for(int j=0;j<6;j++){
    #pragma unroll
    for(int r=0;r<4;r++){
      int rel = 16*j + r16 - 16 - (rowb + r);
      bool ok = (rel >= -16) && (rel < 16) && (s_base + 16*j + r16 >= 0);
      if(ok){
        ser[r] += __expf(sacc[j][r] - m1r[r]);
        wpr[r] += dacc[j][r];
      }
    }
  }
  #pragma unroll
  for(int r=0;r<4;r++){
    ser[r] += __shfl_xor(ser[r], 1); ser[r] += __shfl_xor(ser[r], 2);
    ser[r] += __shfl_xor(ser[r], 4); ser[r] += __shfl_xor(ser[r], 8);
    wpr[r] += __shfl_xor(wpr[r], 1); wpr[r] += __shfl_xor(wpr[r], 2);
    wpr[r] += __shfl_xor(wpr[r], 4); wpr[r] += __shfl_xor(wpr[r], 8);
  }
  float lnr[4], scr[4];
  #pragma unroll
  for(int r=0;r<4;r++){
    float qk_lse = m1r[r] + __logf(ser[r]);
    float lrem = fmaxf(lr1r[r] - wpr[r], 1e-37f);
    float bb = __logf(lrem) + plsr[r];
    float ln = fmaxf(qk_lse, bb) + log1pf(__expf(-fabsf(qk_lse - bb)));
    lnr[r] = ln;
    scr[r] = __expf(plsr[r] - ln);
  }
  #pragma unroll
  for(int j=0;j<6;j++){
    #pragma unroll
    for(int r=0;r<4;r++){
      int rel = 16*j + r16 - 16 - (rowb + r);
      bool ok = (rel >= -16) && (rel < 16) && (s_base + 16*j + r16 >= 0);
      float cj = ok ? (__expf(sacc[j][r] - lnr[r]) - scr[r]*dacc[j][r]) : 0.f;
      u16 hb = f2b(cj);
      int row = rowb + r;
      int col = (16*j + r16) ^ (8*((row>>2)&7));   // col <= 127 < 136 safe
      cjh[row*136 + col] = hb;
      cjl[row*136 + col] = f2b(cj - b2f(hb));
    }
  }
  __syncthreads();

  // ---- B3: out = cj . v_win (hi/lo split) + scale*lr_v (lacc, f32)
  f32x4 oacc[4];
  #pragma unroll
  for(int dt=0;dt<4;dt++) oacc[dt] = zero4;
  const int qrowB = wave*16 + r16;
  const int cw = (qrowB >> 2) & 7;
  #pragma unroll
  for(int ks=0;ks<3;ks++){
    int ccol = (ks*32 + g*8) ^ (8*cw);
    short8 ch = *(const short8*)(cjh + qrowB*136 + ccol);
    short8 cl = *(const short8*)(cjl + qrowB*136 + ccol);
    #pragma unroll
    for(int dt=0;dt<4;dt++){
      int vrow = dt*16 + r16;
      int vcol = (ks*32 + g*8) ^ (8*((vrow>>2)&3));
      short8 vbh = *(const short8*)(vt  + vrow*104 + vcol);
      short8 vbl = *(const short8*)(vtl + vrow*104 + vcol);
      oacc[dt] = __builtin_amdgcn_mfma_f32_16x16x32_bf16(ch, vbh, oacc[dt], 0, 0, 0);
      oacc[dt] = __builtin_amdgcn_mfma_f32_16x16x32_bf16(cl, vbh, oacc[dt], 0, 0, 0);
      oacc[dt] = __builtin_amdgcn_mfma_f32_16x16x32_bf16(ch, vbl, oacc[dt], 0, 0, 0);
    }
  }
  #pragma unroll
  for(int r=0;r<4;r++){
    int row = rowb + r;                      // query within 64
    float* ob = out + ((((size_t)b*8 + h)*4096) + (size_t)c*1024 + qt*64 + row)*64;
    #pragma unroll
    for(int dt=0;dt<4;dt++)
      ob[dt*16 + r16] = oacc[dt][r] + scr[r]*lacc[dt][r];
  }
}

extern "C" void kernel_launch(void* const* d_in, const int* in_sizes, int n_in,
                              void* d_out, int out_size, void* d_ws, size_t ws_size,
                              hipStream_t stream){
  (void)in_sizes; (void)n_in; (void)out_size; (void)ws_size;
  const float* q = (const float*)d_in[0];
  const float* k = (const float*)d_in[1];
  const float* v = (const float*)d_in[2];
  const float* p = (const float*)d_in[3];
  float* out = (float*)d_out;
  float* ws = (float*)d_ws;
  hipMemsetAsync(ws + WS_K1, 0, (size_t)(16384 + 1048576)*sizeof(float), stream);
  k_stab<<<dim3(4),      128, 0, stream>>>(p, ws);
  k_phi <<<dim3(4,128),  256, 0, stream>>>(k, v, p, ws);
  k_qm  <<<dim3(16,128), 256, 0, stream>>>(q, k, v, p, ws, out);
}

// Round 12
// 307.811 us; speedup vs baseline: 1.2836x; 1.0264x over previous
//
#include <hip/hip_runtime.h>

typedef unsigned short u16;
typedef unsigned int   u32;
typedef __attribute__((ext_vector_type(8))) short short8;
typedef __attribute__((ext_vector_type(4))) float f32x4;

#define LOGM 4.852030263919617f

// workspace layout (float offsets)
constexpr int WS_PMAX = 0;         // 128 floats (per-combo stabilizer bound, by k_zs)
constexpr int WS_K1   = 2048;      // 128*128 floats (k1sum, atomic-accumulated)
constexpr int WS_KV   = 18432;     // 128*128*64 floats (kv [m][d], atomic-accumulated)
constexpr int WS_PHIK = 1067008;   // u16: 128 combos * 1056 * 128 (phi_k bf16, [s][m])

__device__ __forceinline__ float b2f(u16 u){ union { u32 i; float f; } x; x.i = ((u32)u) << 16; return x.f; }
__device__ __forceinline__ u16 f2b(float f){ union { float f; u32 i; } x; x.f = f; return (u16)((x.i + 0x7fffu + ((x.i >> 16) & 1u)) >> 16); }

// ========= k_zs: zero WS_K1+WS_KV (1040*256 float4 = 266240 exactly) + stab =========
__global__ __launch_bounds__(256) void k_zs(const float* __restrict__ proj,
                                            float* __restrict__ ws){
  __shared__ float red[2];
  const int bid = blockIdx.x, tid = threadIdx.x;
  const float4 z = {0.f,0.f,0.f,0.f};
  *(float4*)(ws + WS_K1 + ((size_t)bid*256 + tid)*4) = z;
  if(bid < 4 && tid < 128){
    const float4* pr = (const float4*)(proj + bid*8192 + tid*64);
    float pn = 0.f;
    #pragma unroll
    for(int i=0;i<16;i++){ float4 u = pr[i]; pn = fmaf(u.x,u.x,fmaf(u.y,u.y,fmaf(u.z,u.z,fmaf(u.w,u.w,pn)))); }
    #pragma unroll
    for(int o=1;o<64;o<<=1) pn = fmaxf(pn, __shfl_xor(pn, o));
    if((tid & 63) == 0) red[tid >> 6] = pn;
  }
  __syncthreads();
  if(bid < 4 && tid < 32){
    const float stab = 0.5f * fmaxf(red[0], red[1]);
    ws[WS_PMAX + bid*32 + tid] = stab;   // all combos with this c
  }
}

// ================= k_phi: logk MFMA -> phi_k -> ws; kv & k1 atomics =================
// r9: interleaved tile map + hoisted stab (122 us). r12: tile order additionally
// ROTATED by (combo&3)*4 so co-resident blocks are phase-shifted — one block's
// MFMA phase overlaps the other's load/barrier phase (convoy break). Same tile
// set, traffic-identical; kv/k1 accumulation order shifts (already nondet via atomics).
__global__ __launch_bounds__(256, 2) void k_phi(const float* __restrict__ key,
                                                const float* __restrict__ val,
                                                const float* __restrict__ proj,
                                                float* __restrict__ ws){
  __shared__ __align__(16) u16 phit[128*72];   // [m][key64] bf16, stride 72
  __shared__ __align__(16) u16 vt[64*72];      // [d][key64] bf16, stride 72, col-swizzled
  const int tid = threadIdx.x;
  const int wave = tid >> 6, l = tid & 63;
  const int g = l >> 4, r16 = l & 15;
  const int kq = blockIdx.x, combo = blockIdx.y;
  const int c = combo >> 5, b = (combo >> 3) & 3, h = combo & 7;
  const float* projc = proj + c*8192;
  const float stab = ws[WS_PMAX + combo];
  const int rot = (combo & 3) << 2;            // 0,4,8,12 — de-phase co-resident blocks

  short8 ph[8][2], pl[8][2];
  #pragma unroll
  for(int mt=0;mt<8;mt++){
    #pragma unroll
    for(int ks=0;ks<2;ks++){
      const float* pb = projc + (mt*16 + r16)*64 + ks*32 + g*8;
      float4 u0 = *(const float4*)pb;
      float4 u1 = *(const float4*)(pb + 4);
      float x[8] = {u0.x,u0.y,u0.z,u0.w,u1.x,u1.y,u1.z,u1.w};
      #pragma unroll
      for(int j=0;j<8;j++){
        u16 hb = f2b(x[j]);
        ph[mt][ks][j] = (short)hb;
        pl[mt][ks][j] = (short)f2b(x[j] - b2f(hb));
      }
    }
  }

  const f32x4 zero4 = {0.f,0.f,0.f,0.f};
  f32x4 kvacc[2][4];
  #pragma unroll
  for(int i=0;i<2;i++)
    #pragma unroll
    for(int j=0;j<4;j++) kvacc[i][j] = zero4;
  float k1p0 = 0.f, k1p1 = 0.f;
  u16* phikg = ((u16*)(ws + WS_PHIK)) + (size_t)combo*1056*128;

  for(int t0=0;t0<16;t0++){
    const int tt = (t0 + rot) & 15;
    const int s_tile = (kq + 4*tt)*64;      // interleaved tile map (rotated start)
    const bool dtile = (s_tile < 1056);
    const int sA = s_tile + wave*16 + r16;
    const float* krow = key + (size_t)(b*4096 + sA)*512 + h*64;
    float areg[16];
    #pragma unroll
    for(int ks=0;ks<2;ks++){
      float4 u0 = *(const float4*)(krow + ks*32 + g*8);
      float4 u1 = *(const float4*)(krow + ks*32 + g*8 + 4);
      areg[ks*8+0]=u0.x; areg[ks*8+1]=u0.y; areg[ks*8+2]=u0.z; areg[ks*8+3]=u0.w;
      areg[ks*8+4]=u1.x; areg[ks*8+5]=u1.y; areg[ks*8+6]=u1.z; areg[ks*8+7]=u1.w;
    }
    float4 vreg[4];
    #pragma unroll
    for(int i=0;i<4;i++){
      int flat = tid + 256*i;
      int sv = flat >> 4, d4 = (flat & 15)*4;
      vreg[i] = *(const float4*)(val + (size_t)(b*4096 + s_tile + sv)*512 + h*64 + d4);
    }
    float ksq = 0.f;
    #pragma unroll
    for(int e=0;e<16;e++) ksq = fmaf(areg[e], areg[e], ksq);
    ksq += __shfl_xor(ksq, 16);
    ksq += __shfl_xor(ksq, 32);
    ksq *= 0.5f;
    short8 ah[2], al[2];
    #pragma unroll
    for(int ks=0;ks<2;ks++){
      #pragma unroll
      for(int j=0;j<8;j++){
        float x = areg[ks*8+j];
        u16 hb = f2b(x);
        ah[ks][j] = (short)hb;
        al[ks][j] = (short)f2b(x - b2f(hb));
      }
    }
    f32x4 acc[8];
    #pragma unroll
    for(int mt=0;mt<8;mt++) acc[mt] = zero4;
    #pragma unroll
    for(int ks=0;ks<2;ks++){
      #pragma unroll
      for(int mt=0;mt<8;mt++){
        acc[mt] = __builtin_amdgcn_mfma_f32_16x16x32_bf16(ah[ks], ph[mt][ks], acc[mt], 0, 0, 0);
        acc[mt] = __builtin_amdgcn_mfma_f32_16x16x32_bf16(ah[ks], pl[mt][ks], acc[mt], 0, 0, 0);
        acc[mt] = __builtin_amdgcn_mfma_f32_16x16x32_bf16(al[ks], ph[mt][ks], acc[mt], 0, 0, 0);
      }
    }
    const float kc0 = __shfl(ksq, 4*g + 0);
    const float kc1 = __shfl(ksq, 4*g + 1);
    const float kc2 = __shfl(ksq, 4*g + 2);
    const float kc3 = __shfl(ksq, 4*g + 3);
    const int gs = s_tile + wave*16 + r16;
    #pragma unroll
    for(int mt=0;mt<8;mt++){
      ushort4 pw;
      pw.x = f2b(__expf(acc[mt][0] - kc0 - stab));
      pw.y = f2b(__expf(acc[mt][1] - kc1 - stab));
      pw.z = f2b(__expf(acc[mt][2] - kc2 - stab));
      pw.w = f2b(__expf(acc[mt][3] - kc3 - stab));
      *(ushort4*)(phit + (mt*16 + r16)*72 + wave*16 + 4*g) = pw;
      if(dtile && gs < 1056)
        *(ushort4*)(phikg + (size_t)gs*128 + mt*16 + 4*g) = pw;
    }
    #pragma unroll
    for(int i=0;i<4;i++){
      int flat = tid + 256*i;
      int sv = flat >> 4, d4 = (flat & 15)*4;
      float x[4] = {vreg[i].x, vreg[i].y, vreg[i].z, vreg[i].w};
      #pragma unroll
      for(int j=0;j<4;j++){
        int d = d4 + j;
        vt[d*72 + (sv ^ (8*((d>>2)&7)))] = f2b(x[j]);
      }
    }
    __syncthreads();
    #pragma unroll
    for(int ks=0;ks<2;ks++){
      short8 af0 = *(const short8*)(phit + ((2*wave+0)*16 + r16)*72 + ks*32 + g*8);
      short8 af1 = *(const short8*)(phit + ((2*wave+1)*16 + r16)*72 + ks*32 + g*8);
      short8 bf[4];
      #pragma unroll
      for(int dt=0;dt<4;dt++){
        int d = dt*16 + r16;
        int col = (ks*32 + g*8) ^ (8*((d>>2)&7));
        bf[dt] = *(const short8*)(vt + d*72 + col);
      }
      #pragma unroll
      for(int dt=0;dt<4;dt++){
        kvacc[0][dt] = __builtin_amdgcn_mfma_f32_16x16x32_bf16(af0, bf[dt], kvacc[0][dt], 0, 0, 0);
        kvacc[1][dt] = __builtin_amdgcn_mfma_f32_16x16x32_bf16(af1, bf[dt], kvacc[1][dt], 0, 0, 0);
      }
      #pragma unroll
      for(int j=0;j<8;j++){ k1p0 += b2f((u16)af0[j]); k1p1 += b2f((u16)af1[j]); }
    }
    __syncthreads();
  }
  k1p0 += __shfl_xor(k1p0, 16); k1p0 += __shfl_xor(k1p0, 32);
  k1p1 += __shfl_xor(k1p1, 16); k1p1 += __shfl_xor(k1p1, 32);
  if(l < 16){
    atomicAdd(ws + WS_K1 + combo*128 + (2*wave+0)*16 + l, k1p0);
    atomicAdd(ws + WS_K1 + combo*128 + (2*wave+1)*16 + l, k1p1);
  }
  #pragma unroll
  for(int mi=0;mi<2;mi++){
    #pragma unroll
    for(int dt=0;dt<4;dt++){
      #pragma unroll
      for(int rr=0;rr<4;rr++){
        int m = (2*wave+mi)*16 + 4*g + rr;
        int d = dt*16 + r16;
        atomicAdd(ws + WS_KV + (size_t)combo*8192 + m*64 + d, kvacc[mi][dt][rr]);
      }
    }
  }
}

// ================= k_qm: fused k_q + k_main (r11: T14 hoist + write-swizzles) =====
__global__ __launch_bounds__(256, 2) void k_qm(const float* __restrict__ qry,
                                               const float* __restrict__ key,
                                               const float* __restrict__ val,
                                               const float* __restrict__ proj,
                                               float* __restrict__ ws,
                                               float* __restrict__ out){
  __shared__ __align__(16) u16 buf[30720];   // 61440 B
  // phase A layout
  u16* kvtA   = buf;            // [d][m] stride 136, col-swizzled
  u16* phiqsA = buf + 8704;     // [q][m] stride 136
  float* k1s  = (float*)(buf + 17408);   // 128 floats
  // phase B layout (overlays; all phase-A reads complete before reuse)
  u16* khs  = buf;              // [96][72]
  u16* kls  = buf + 6912;
  u16* phik = buf + 13824;      // [96][136]
  u16* cjh  = buf;              // [64][136], col-swizzled
  u16* cjl  = buf + 8704;
  u16* vt   = buf + 17408;      // [64][104], col-swizzled
  u16* vtl  = buf + 24064;

  const int tid = threadIdx.x;
  const int wave = tid >> 6, l = tid & 63;
  const int g = l >> 4, r16 = l & 15;
  const int qt = blockIdx.x, combo = blockIdx.y;
  const int c = combo >> 5, b = (combo >> 3) & 3, h = combo & 7;
  const int s_base = qt*64 - 16;
  const float* projc = proj + c*8192;
  const float stab = ws[WS_PMAX + combo];
  const f32x4 zero4 = {0.f,0.f,0.f,0.f};

  // ---- prefetch ALL phase-B global inputs (consumed after A2) — T14
  const u16* phikg = ((const u16*)(ws + WS_PHIK)) + (size_t)combo*1056*128;
  float4 kreg[6], vreg[6];
  ushort4 preg[12];
  #pragma unroll
  for(int i=0;i<6;i++){
    int flat = tid + 256*i;
    int j = flat >> 4, e4 = (flat & 15)*4;
    int s = s_base + j;
    float4 u = {0.f,0.f,0.f,0.f};
    float4 w4 = {0.f,0.f,0.f,0.f};
    if(s >= 0){
      u  = *(const float4*)(key + (((size_t)b*4096 + s)*8 + h)*64 + e4);
      w4 = *(const float4*)(val + (((size_t)b*4096 + s)*8 + h)*64 + e4);
    }
    kreg[i] = u; vreg[i] = w4;
  }
  #pragma unroll
  for(int i=0;i<12;i++){
    int flat = tid + 256*i;
    int j = flat >> 5, c4 = (flat & 31)*4;
    int s = s_base + j;
    ushort4 p = {0,0,0,0};
    if(s >= 0) p = *(const ushort4*)(phikg + (size_t)s*128 + c4);
    preg[i] = p;
  }

  // ---- A0: k1s + kv -> LDS (transposed bf16, col-swizzled)
  if(tid < 128) k1s[tid] = ws[WS_K1 + combo*128 + tid];
  const float* kvg = ws + WS_KV + (size_t)combo*8192;
  #pragma unroll
  for(int i=0;i<8;i++){
    int flat = tid + 256*i;
    int m = flat >> 4, d4 = (flat & 15)*4;
    int col = m ^ (8*((flat & 15) & 7));   // swz by (d>>2)&7 = (flat&15)&7
    float4 u = *(const float4*)(kvg + m*64 + d4);
    kvtA[(d4+0)*136 + col] = f2b(u.x);
    kvtA[(d4+1)*136 + col] = f2b(u.y);
    kvtA[(d4+2)*136 + col] = f2b(u.z);
    kvtA[(d4+3)*136 + col] = f2b(u.w);
  }
  // q fragments (hi/lo) — used by BOTH logq (phase A) and scores (phase B)
  const int qrow = qt*64 + wave*16 + r16;
  const float* qr = qry + (size_t)(b*4096 + (c*1024 + qrow))*512 + h*64;
  float areg[16];
  #pragma unroll
  for(int ks=0;ks<2;ks++){
    float4 u0 = *(const float4*)(qr + ks*32 + g*8);
    float4 u1 = *(const float4*)(qr + ks*32 + g*8 + 4);
    areg[ks*8+0]=u0.x; areg[ks*8+1]=u0.y; areg[ks*8+2]=u0.z; areg[ks*8+3]=u0.w;
    areg[ks*8+4]=u1.x; areg[ks*8+5]=u1.y; areg[ks*8+6]=u1.z; areg[ks*8+7]=u1.w;
  }
  float qsq = 0.f;
  #pragma unroll
  for(int e=0;e<16;e++) qsq = fmaf(areg[e], areg[e], qsq);
  qsq += __shfl_xor(qsq, 16);
  qsq += __shfl_xor(qsq, 32);
  qsq *= 0.5f;
  short8 ah[2], al[2];
  #pragma unroll
  for(int ks=0;ks<2;ks++){
    #pragma unroll
    for(int j=0;j<8;j++){
      float x = areg[ks*8+j];
      u16 hb = f2b(x);
      ah[ks][j] = (short)hb;
      al[ks][j] = (short)f2b(x - b2f(hb));
    }
  }
  __syncthreads();   // kvtA, k1s ready

  // ---- A1: logq MFMA
  f32x4 acc[8];
  #pragma unroll
  for(int mt=0;mt<8;mt++) acc[mt] = zero4;
  #pragma unroll
  for(int ks=0;ks<2;ks++){
    #pragma unroll
    for(int mt=0;mt<8;mt++){
      const float* pb = projc + (mt*16 + r16)*64 + ks*32 + g*8;
      float4 u0 = *(const float4*)pb;
      float4 u1 = *(const float4*)(pb + 4);
      float x[8] = {u0.x,u0.y,u0.z,u0.w,u1.x,u1.y,u1.z,u1.w};
      short8 pph, ppl;
      #pragma unroll
      for(int j=0;j<8;j++){
        u16 hb = f2b(x[j]);
        pph[j] = (short)hb;
        ppl[j] = (short)f2b(x[j] - b2f(hb));
      }
      acc[mt] = __builtin_amdgcn_mfma_f32_16x16x32_bf16(ah[ks], pph, acc[mt], 0, 0, 0);
      acc[mt] = __builtin_amdgcn_mfma_f32_16x16x32_bf16(ah[ks], ppl, acc[mt], 0, 0, 0);
      acc[mt] = __builtin_amdgcn_mfma_f32_16x16x32_bf16(al[ks], pph, acc[mt], 0, 0, 0);
    }
  }
  float qsr[4];
  #pragma unroll
  for(int r=0;r<4;r++) qsr[r] = __shfl(qsq, 4*g + r);
  float amax[4];
  #pragma unroll
  for(int r=0;r<4;r++){
    float m = -3e38f;
    #pragma unroll
    for(int mt=0;mt<8;mt++) m = fmaxf(m, acc[mt][r]);
    m = fmaxf(m, __shfl_xor(m, 1));
    m = fmaxf(m, __shfl_xor(m, 2));
    m = fmaxf(m, __shfl_xor(m, 4));
    m = fmaxf(m, __shfl_xor(m, 8));
    amax[r] = m;
  }
  float lrp[4] = {0.f,0.f,0.f,0.f};
  #pragma unroll
  for(int mt=0;mt<8;mt++){
    const float k1v = k1s[mt*16 + r16];
    #pragma unroll
    for(int r=0;r<4;r++){
      float phv = __expf(acc[mt][r] - amax[r]);
      phiqsA[(wave*16 + 4*g + r)*136 + mt*16 + r16] = f2b(phv);
      lrp[r] = fmaf(phv, k1v, lrp[r]);
    }
  }
  #pragma unroll
  for(int r=0;r<4;r++){
    lrp[r] += __shfl_xor(lrp[r], 1);
    lrp[r] += __shfl_xor(lrp[r], 2);
    lrp[r] += __shfl_xor(lrp[r], 4);
    lrp[r] += __shfl_xor(lrp[r], 8);
  }
  float plsr[4], lr1r[4];
  #pragma unroll
  for(int r=0;r<4;r++){
    plsr[r] = amax[r] - qsr[r] + stab - LOGM;
    lr1r[r] = lrp[r];
  }
  __syncthreads();   // phiqsA complete

  // ---- A2: phi_q A-fragments + lr_v MFMA (f32, kept in regs)
  short8 pa[4];
  #pragma unroll
  for(int ks=0;ks<4;ks++)
    pa[ks] = *(const short8*)(phiqsA + (wave*16 + r16)*136 + ks*32 + g*8);
  f32x4 lacc[4];
  #pragma unroll
  for(int dt=0;dt<4;dt++) lacc[dt] = zero4;
  #pragma unroll
  for(int ks=0;ks<4;ks++){
    #pragma unroll
    for(int dt=0;dt<4;dt++){
      int drow = dt*16 + r16;
      int colb = (ks*32 + g*8) ^ (8*((drow>>2)&7));
      short8 bfr = *(const short8*)(kvtA + drow*136 + colb);
      lacc[dt] = __builtin_amdgcn_mfma_f32_16x16x32_bf16(pa[ks], bfr, lacc[dt], 0, 0, 0);
    }
  }
  __syncthreads();   // all phase-A LDS reads done; buf may be overwritten

  // ---- B0: write prefetched k window (hi/lo) + phi_k window to LDS
  #pragma unroll
  for(int i=0;i<6;i++){
    int flat = tid + 256*i;
    int j = flat >> 4, e4 = (flat & 15)*4;
    float4 u = kreg[i];
    ushort4 hh, ll;
    hh.x = f2b(u.x); ll.x = f2b(u.x - b2f(hh.x));
    hh.y = f2b(u.y); ll.y = f2b(u.y - b2f(hh.y));
    hh.z = f2b(u.z); ll.z = f2b(u.z - b2f(hh.z));
    hh.w = f2b(u.w); ll.w = f2b(u.w - b2f(hh.w));
    *(ushort4*)(khs + j*72 + e4) = hh;
    *(ushort4*)(kls + j*72 + e4) = ll;
  }
  #pragma unroll
  for(int i=0;i<12;i++){
    int flat = tid + 256*i;
    int j = flat >> 5, c4 = (flat & 31)*4;
    *(ushort4*)(phik + j*136 + c4) = preg[i];
  }
  __syncthreads();

  // ---- B1: S (scores) and D (dots_p) over the full 16x96 stripe
  f32x4 sacc[6], dacc[6];
  #pragma unroll
  for(int j=0;j<6;j++){ sacc[j] = zero4; dacc[j] = zero4; }
  #pragma unroll
  for(int j=0;j<6;j++){
    #pragma unroll
    for(int ks=0;ks<2;ks++){
      short8 kbh = *(const short8*)(khs + (j*16 + r16)*72 + ks*32 + g*8);
      short8 kbl = *(const short8*)(kls + (j*16 + r16)*72 + ks*32 + g*8);
      sacc[j] = __builtin_amdgcn_mfma_f32_16x16x32_bf16(ah[ks], kbh, sacc[j], 0, 0, 0);
      sacc[j] = __builtin_amdgcn_mfma_f32_16x16x32_bf16(al[ks], kbh, sacc[j], 0, 0, 0);
      sacc[j] = __builtin_amdgcn_mfma_f32_16x16x32_bf16(ah[ks], kbl, sacc[j], 0, 0, 0);
    }
    #pragma unroll
    for(int ks=0;ks<4;ks++){
      short8 pb = *(const short8*)(phik + (j*16 + r16)*136 + ks*32 + g*8);
      dacc[j] = __builtin_amdgcn_mfma_f32_16x16x32_bf16(pa[ks], pb, dacc[j], 0, 0, 0);
    }
  }
  __syncthreads();   // all B1 LDS reads done; region reused below

  // ---- B2: v -> LDS (transposed, hi/lo, col-swizzled); softmax; cj -> LDS (swizzled)
  #pragma unroll
  for(int i=0;i<6;i++){
    int flat = tid + 256*i;
    int j = flat >> 4, e4 = (flat & 15)*4;
    int e = flat & 15;
    int col = j ^ (8*(e & 3));             // swz by (row>>2)&3 = e&3; col <= 95 safe
    float4 u = vreg[i];
    u16 h0 = f2b(u.x), h1 = f2b(u.y), h2 = f2b(u.z), h3 = f2b(u.w);
    vt[(e4+0)*104 + col] = h0; vtl[(e4+0)*104 + col] = f2b(u.x - b2f(h0));
    vt[(e4+1)*104 + col] = h1; vtl[(e4+1)*104 + col] = f2b(u.y - b2f(h1));
    vt[(e4+2)*104 + col] = h2; vtl[(e4+2)*104 + col] = f2b(u.z - b2f(h2));
    vt[(e4+3)*104 + col] = h3; vtl[(e4+3)*104 + col] = f2b(u.w - b2f(h3));
  }
  const int rowb = wave*16 + 4*g;
  float m1r[4] = {-1e30f,-1e30f,-1e30f,-1e30f};
  #pragma unroll
  for(int j=0;j<6;j++){
    #pragma unroll
    for(int r=0;r<4;r++){
      int rel = 16*j + r16 - 16 - (rowb + r);
      bool ok = (rel >= -16) && (rel < 16) && (s_base + 16*j + r16 >= 0);
      if(ok) m1r[r] = fmaxf(m1r[r], sacc[j][r]);
    }
  }
  #pragma unroll
  for(int r=0;r<4;r++){
    m1r[r] = fmaxf(m1r[r], __shfl_xor(m1r[r], 1));
    m1r[r] = fmaxf(m1r[r], __shfl_xor(m1r[r], 2));
    m1r[r] = fmaxf(m1r[r], __shfl_xor(m1r[r], 4));
    m1r[r] = fmaxf(m1r[r], __shfl_xor(m1r[r], 8));
  }
  float ser[4] = {0.f,0.f,0.f,0.f}, wpr[4] = {0.f,0.f,0.f,0.f};
  #pragma unroll
  for(int j=0;j<6;j++){
    #pragma unroll
    for(int r=0;r<4;r++){
      int rel = 16*j + r16 - 16 - (rowb + r);
      bool ok = (rel >= -16) && (rel < 16) && (s_base + 16*j + r16 >= 0);
      if(ok){
        ser[r] += __expf(sacc[j][r] - m1r[r]);
        wpr[r] += dacc[j][r];
      }
    }
  }
  #pragma unroll
  for(int r=0;r<4;r++){
    ser[r] += __shfl_xor(ser[r], 1); ser[r] += __shfl_xor(ser[r], 2);
    ser[r] += __shfl_xor(ser[r], 4); ser[r] += __shfl_xor(ser[r], 8);
    wpr[r] += __shfl_xor(wpr[r], 1); wpr[r] += __shfl_xor(wpr[r], 2);
    wpr[r] += __shfl_xor(wpr[r], 4); wpr[r] += __shfl_xor(wpr[r], 8);
  }
  float lnr[4], scr[4];
  #pragma unroll
  for(int r=0;r<4;r++){
    float qk_lse = m1r[r] + __logf(ser[r]);
    float lrem = fmaxf(lr1r[r] - wpr[r], 1e-37f);
    float bb = __logf(lrem) + plsr[r];
    float ln = fmaxf(qk_lse, bb) + log1pf(__expf(-fabsf(qk_lse - bb)));
    lnr[r] = ln;
    scr[r] = __expf(plsr[r] - ln);
  }
  #pragma unroll
  for(int j=0;j<6;j++){
    #pragma unroll
    for(int r=0;r<4;r++){
      int rel = 16*j + r16 - 16 - (rowb + r);
      bool ok = (rel >= -16) && (rel < 16) && (s_base + 16*j + r16 >= 0);
      float cj = ok ? (__expf(sacc[j][r] - lnr[r]) - scr[r]*dacc[j][r]) : 0.f;
      u16 hb = f2b(cj);
      int row = rowb + r;
      int col = (16*j + r16) ^ (8*((row>>2)&7));   // col <= 127 < 136 safe
      cjh[row*136 + col] = hb;
      cjl[row*136 + col] = f2b(cj - b2f(hb));
    }
  }
  __syncthreads();

  // ---- B3: out = cj . v_win (hi/lo split) + scale*lr_v (lacc, f32)
  f32x4 oacc[4];
  #pragma unroll
  for(int dt=0;dt<4;dt++) oacc[dt] = zero4;
  const int qrowB = wave*16 + r16;
  const int cw = (qrowB >> 2) & 7;
  #pragma unroll
  for(int ks=0;ks<3;ks++){
    int ccol = (ks*32 + g*8) ^ (8*cw);
    short8 ch = *(const short8*)(cjh + qrowB*136 + ccol);
    short8 cl = *(const short8*)(cjl + qrowB*136 + ccol);
    #pragma unroll
    for(int dt=0;dt<4;dt++){
      int vrow = dt*16 + r16;
      int vcol = (ks*32 + g*8) ^ (8*((vrow>>2)&3));
      short8 vbh = *(const short8*)(vt  + vrow*104 + vcol);
      short8 vbl = *(const short8*)(vtl + vrow*104 + vcol);
      oacc[dt] = __builtin_amdgcn_mfma_f32_16x16x32_bf16(ch, vbh, oacc[dt], 0, 0, 0);
      oacc[dt] = __builtin_amdgcn_mfma_f32_16x16x32_bf16(cl, vbh, oacc[dt], 0, 0, 0);
      oacc[dt] = __builtin_amdgcn_mfma_f32_16x16x32_bf16(ch, vbl, oacc[dt], 0, 0, 0);
    }
  }
  #pragma unroll
  for(int r=0;r<4;r++){
    int row = rowb + r;                      // query within 64
    float* ob = out + ((((size_t)b*8 + h)*4096) + (size_t)c*1024 + qt*64 + row)*64;
    #pragma unroll
    for(int dt=0;dt<4;dt++)
      ob[dt*16 + r16] = oacc[dt][r] + scr[r]*lacc[dt][r];
  }
}

extern "C" void kernel_launch(void* const* d_in, const int* in_sizes, int n_in,
                              void* d_out, int out_size, void* d_ws, size_t ws_size,
                              hipStream_t stream){
  (void)in_sizes; (void)n_in; (void)out_size; (void)ws_size;
  const float* q = (const float*)d_in[0];
  const float* k = (const float*)d_in[1];
  const float* v = (const float*)d_in[2];
  const float* p = (const float*)d_in[3];
  float* out = (float*)d_out;
  float* ws = (float*)d_ws;
  k_zs  <<<dim3(1040),   256, 0, stream>>>(p, ws);
  k_phi <<<dim3(4,128),  256, 0, stream>>>(k, v, p, ws);
  k_qm  <<<dim3(16,128), 256, 0, stream>>>(q, k, v, p, ws, out);
}